// Round 2
// baseline (1767.600 us; speedup 1.0000x reference)
//
#include <hip/hip_runtime.h>
#include <hip/hip_bf16.h>
#include <math.h>

// Problem constants
#define BB 2
#define SS 2048
#define DD 2048
#define HH 16
#define CONVC 6144
#define MM (BB*SS)   // 4096 tokens

typedef __bf16 bf16_t;
typedef __bf16 bf16x8 __attribute__((ext_vector_type(8)));
typedef __bf16 bf16x4 __attribute__((ext_vector_type(4)));
typedef float  f32x4  __attribute__((ext_vector_type(4)));

#define GLOBAL_AS __attribute__((address_space(1)))
#define LDS_AS    __attribute__((address_space(3)))

// ---------------------------------------------------------------------------
// Cast kernels
// ---------------------------------------------------------------------------
__global__ __launch_bounds__(256) void cast_x_kernel(
    const float* __restrict__ in, const float* __restrict__ mask,
    bf16_t* __restrict__ out, long n)
{
  long n4 = n >> 2;
  for (long i = (long)blockIdx.x*256 + threadIdx.x; i < n4; i += (long)gridDim.x*256) {
    float4 v = ((const float4*)in)[i];
    float m = mask[(i*4) / DD];
    bf16x4 o4;
    o4[0]=(bf16_t)(v.x*m); o4[1]=(bf16_t)(v.y*m);
    o4[2]=(bf16_t)(v.z*m); o4[3]=(bf16_t)(v.w*m);
    ((bf16x4*)out)[i] = o4;
  }
}

__global__ __launch_bounds__(256) void cast_w_kernel(
    const float* __restrict__ in, bf16_t* __restrict__ out, long n)
{
  long n4 = n >> 2;
  for (long i = (long)blockIdx.x*256 + threadIdx.x; i < n4; i += (long)gridDim.x*256) {
    float4 v = ((const float4*)in)[i];
    bf16x4 o4;
    o4[0]=(bf16_t)v.x; o4[1]=(bf16_t)v.y; o4[2]=(bf16_t)v.z; o4[3]=(bf16_t)v.w;
    ((bf16x4*)out)[i] = o4;
  }
}

// ---------------------------------------------------------------------------
// bf16 MFMA GEMM: C[M,N] = A[M,K] * B[N,K]^T   (m97-style 128x128 tile, BK=32)
// ---------------------------------------------------------------------------
template<bool OUT_BF16>
__global__ __launch_bounds__(256) void gemm_bt(
    const bf16_t* __restrict__ A, const bf16_t* __restrict__ Bm,
    void* __restrict__ Cp, int M, int N, int K)
{
  __shared__ __align__(16) bf16_t lA[128*32];
  __shared__ __align__(16) bf16_t lB[128*32];
  const int t    = threadIdx.x;
  const int lane = t & 63;
  const int w    = t >> 6;       // wave 0..3
  const int wm   = w >> 1, wn = w & 1;
  const int fr   = lane & 15, fq = lane >> 4;
  const long bm  = blockIdx.x, bn = blockIdx.y;

  f32x4 acc[4][4];
  #pragma unroll
  for (int i=0;i<4;i++)
    #pragma unroll
    for (int jj=0;jj<4;jj++) acc[i][jj] = (f32x4){0.f,0.f,0.f,0.f};

  // staging: thread t's 16B chunk covers tile row t>>2, k-elems ((t&3)*8..+8)
  const int r1 = t >> 2;
  const int kb = (t & 3) << 3;
  const bf16_t* a0 = A  + (bm*128 + r1)*(long)K + kb;
  const bf16_t* a1 = a0 + 64*(long)K;
  const bf16_t* b0 = Bm + (bn*128 + r1)*(long)K + kb;
  const bf16_t* b1 = b0 + 64*(long)K;
  bf16_t* lA0 = lA + (w*64)*8;        // wave-uniform LDS bases
  bf16_t* lA1 = lA + (256 + w*64)*8;
  bf16_t* lB0 = lB + (w*64)*8;
  bf16_t* lB1 = lB + (256 + w*64)*8;

  for (int k0 = 0; k0 < K; k0 += 32) {
    __builtin_amdgcn_global_load_lds((const GLOBAL_AS void*)(a0 + k0), (LDS_AS void*)lA0, 16, 0, 0);
    __builtin_amdgcn_global_load_lds((const GLOBAL_AS void*)(a1 + k0), (LDS_AS void*)lA1, 16, 0, 0);
    __builtin_amdgcn_global_load_lds((const GLOBAL_AS void*)(b0 + k0), (LDS_AS void*)lB0, 16, 0, 0);
    __builtin_amdgcn_global_load_lds((const GLOBAL_AS void*)(b1 + k0), (LDS_AS void*)lB1, 16, 0, 0);
    __syncthreads();   // drains vmcnt before reads

    bf16x8 af[4], bfr[4];
    #pragma unroll
    for (int mi=0;mi<4;mi++)
      af[mi] = *(const bf16x8*)(lA + (wm*64 + mi*16 + fr)*32 + fq*8);
    #pragma unroll
    for (int ni=0;ni<4;ni++)
      bfr[ni] = *(const bf16x8*)(lB + (wn*64 + ni*16 + fr)*32 + fq*8);
    #pragma unroll
    for (int mi=0;mi<4;mi++)
      #pragma unroll
      for (int ni=0;ni<4;ni++)
        acc[mi][ni] = __builtin_amdgcn_mfma_f32_16x16x32_bf16(af[mi], bfr[ni], acc[mi][ni], 0, 0, 0);
    __syncthreads();   // protect LDS before next stage
  }

  #pragma unroll
  for (int mi=0;mi<4;mi++) {
    #pragma unroll
    for (int ni=0;ni<4;ni++) {
      long row = bm*128 + wm*64 + mi*16 + fq*4;
      long col = bn*128 + wn*64 + ni*16 + fr;
      #pragma unroll
      for (int r=0;r<4;r++) {
        float v = acc[mi][ni][r];
        if (OUT_BF16) ((bf16_t*)Cp)[(row+r)*(long)N + col] = (bf16_t)v;
        else          ((float*)Cp)[(row+r)*(long)N + col] = v;
      }
    }
  }
}

// ---------------------------------------------------------------------------
// beta / g:  per token, 16 dots with W_b rows and 16 with W_a rows (K=2048)
// writes beta_t[B,H,S], eg_t[B,H,S] (= exp(g))
// ---------------------------------------------------------------------------
__global__ __launch_bounds__(64) void betag_kernel(
    const bf16_t* __restrict__ xbf, const float* __restrict__ W_b,
    const float* __restrict__ W_a, const float* __restrict__ dt_bias,
    const float* __restrict__ A_log, float* __restrict__ beta_t,
    float* __restrict__ eg_t)
{
  const int row  = blockIdx.x;        // token b*S+s
  const int lane = threadIdx.x;
  const int b = row / SS, s = row % SS;

  float xv[32];
  {
    const bf16x8* xr = (const bf16x8*)(xbf + (long)row*DD + lane*32);
    #pragma unroll
    for (int c8=0;c8<4;c8++) {
      bf16x8 v = xr[c8];
      #pragma unroll
      for (int e=0;e<8;e++) xv[c8*8+e] = (float)v[e];
    }
  }

  for (int h=0; h<HH; ++h) {
    const float4* wb4 = (const float4*)(W_b + (long)h*DD + lane*32);
    const float4* wa4 = (const float4*)(W_a + (long)h*DD + lane*32);
    float pb = 0.f, pa = 0.f;
    #pragma unroll
    for (int c4=0;c4<8;c4++) {
      float4 wb = wb4[c4], wa = wa4[c4];
      pb += xv[c4*4+0]*wb.x + xv[c4*4+1]*wb.y + xv[c4*4+2]*wb.z + xv[c4*4+3]*wb.w;
      pa += xv[c4*4+0]*wa.x + xv[c4*4+1]*wa.y + xv[c4*4+2]*wa.z + xv[c4*4+3]*wa.w;
    }
    #pragma unroll
    for (int off=32; off>=1; off>>=1) { pb += __shfl_xor(pb, off); pa += __shfl_xor(pa, off); }
    if (lane == h) {
      beta_t[((long)b*HH + h)*SS + s] = 1.f/(1.f+expf(-pb));
      float tt = pa + dt_bias[h];
      float sp = (tt > 20.f) ? tt : log1pf(expf(tt));
      float g  = -expf(A_log[h]) * sp;
      eg_t[((long)b*HH + h)*SS + s] = expf(g);
    }
  }
}

// ---------------------------------------------------------------------------
// conv(K=4 causal depthwise) + bias + silu + q/k l2norm + transpose to [B,H,S,128]
// one block per (b,h,s), 128 threads over d. Outputs bf16.
// ---------------------------------------------------------------------------
__global__ __launch_bounds__(128) void conv_norm_kernel(
    const bf16_t* __restrict__ mixed, const float* __restrict__ cw,
    const float* __restrict__ cb, bf16_t* __restrict__ q_t,
    bf16_t* __restrict__ k_t, bf16_t* __restrict__ v_t)
{
  const int blk = blockIdx.x;           // (b*H+h)*S + s
  const int s = blk & (SS-1);
  const int h = (blk >> 11) & (HH-1);
  const int b = blk >> 15;
  const int d = threadIdx.x;

  const int cq = h*128 + d;
  const int ck = 2048 + cq;
  const int cv = 4096 + cq;
  float aq = cb[cq], ak = cb[ck], av = cb[cv];
  const float* wq = cw + (long)cq*4;
  const float* wk = cw + (long)ck*4;
  const float* wv = cw + (long)cv*4;
  #pragma unroll
  for (int tp=0; tp<4; ++tp) {
    int s2 = s - 3 + tp;
    if (s2 >= 0) {
      const bf16_t* rowp = mixed + ((long)b*SS + s2)*CONVC;
      aq += (float)rowp[cq] * wq[tp];
      ak += (float)rowp[ck] * wk[tp];
      av += (float)rowp[cv] * wv[tp];
    }
  }
  aq = aq * (1.f/(1.f+expf(-aq)));
  ak = ak * (1.f/(1.f+expf(-ak)));
  av = av * (1.f/(1.f+expf(-av)));

  float sq = aq*aq, sk = ak*ak;
  #pragma unroll
  for (int off=32; off>=1; off>>=1) { sq += __shfl_xor(sq, off); sk += __shfl_xor(sk, off); }
  __shared__ float red[4];
  const int wv2 = d >> 6;
  if ((d & 63) == 0) { red[wv2*2] = sq; red[wv2*2+1] = sk; }
  __syncthreads();
  float sumq = red[0] + red[2];
  float sumk = red[1] + red[3];

  const long obase = ((long)(b*HH + h)*SS + s)*128 + d;
  q_t[obase] = (bf16_t)(aq * rsqrtf(sumq + 1e-6f) * 0.08838834764831845f);  // * DK^-0.5
  k_t[obase] = (bf16_t)(ak * rsqrtf(sumk + 1e-6f));
  v_t[obase] = (bf16_t)av;
}

// ---------------------------------------------------------------------------
// gated delta rule recurrence. One wave per (b,h, 8-column group).
// lane = cl*8+rg : column j = cg*8+cl, rows i = rg*16..+16 held in VGPRs.
// ---------------------------------------------------------------------------
__global__ __launch_bounds__(64) void rec_kernel(
    const bf16_t* __restrict__ q_t, const bf16_t* __restrict__ k_t,
    const bf16_t* __restrict__ v_t, const float* __restrict__ beta_t,
    const float* __restrict__ eg_t, float* __restrict__ o)
{
  const int blk  = blockIdx.x;       // bh*16 + cg
  const int cg   = blk & 15;
  const int bh   = blk >> 4;
  const int lane = threadIdx.x;
  const int cl   = lane >> 3;
  const int rg   = lane & 7;
  const int j    = cg*8 + cl;
  const int i0   = rg*16;
  const int b    = bh >> 4, h = bh & 15;

  const bf16_t* qb  = q_t + (long)bh*SS*128 + i0;
  const bf16_t* kb  = k_t + (long)bh*SS*128 + i0;
  const bf16_t* vb  = v_t + (long)bh*SS*128 + j;
  const float* egb = eg_t  + (long)bh*SS;
  const float* btb = beta_t + (long)bh*SS;
  float* ob = o + (long)b*SS*HH*128 + h*128 + j;

  float st[16];
  #pragma unroll
  for (int r=0;r<16;r++) st[r] = 0.f;

  float kk[16], qq[16], vv;
  {
    bf16x8 k8a = *(const bf16x8*)(kb);
    bf16x8 k8b = *(const bf16x8*)(kb + 8);
    bf16x8 q8a = *(const bf16x8*)(qb);
    bf16x8 q8b = *(const bf16x8*)(qb + 8);
    #pragma unroll
    for (int e=0;e<8;e++) { kk[e]=(float)k8a[e]; kk[8+e]=(float)k8b[e];
                            qq[e]=(float)q8a[e]; qq[8+e]=(float)q8b[e]; }
    vv = (float)vb[0];
  }

  for (int s=0; s<SS; ++s) {
    const long sn = (s+1 < SS) ? (s+1) : s;
    float nk[16], nq[16], nv;
    {
      bf16x8 k8a = *(const bf16x8*)(kb + sn*128);
      bf16x8 k8b = *(const bf16x8*)(kb + sn*128 + 8);
      bf16x8 q8a = *(const bf16x8*)(qb + sn*128);
      bf16x8 q8b = *(const bf16x8*)(qb + sn*128 + 8);
      #pragma unroll
      for (int e=0;e<8;e++) { nk[e]=(float)k8a[e]; nk[8+e]=(float)k8b[e];
                              nq[e]=(float)q8a[e]; nq[8+e]=(float)q8b[e]; }
      nv = (float)vb[sn*128];
    }

    const float eg  = egb[s];
    const float bet = btb[s];

    float p = 0.f;
    #pragma unroll
    for (int r=0;r<16;r++) { st[r] *= eg; p += kk[r]*st[r]; }
    p += __shfl_xor(p,1); p += __shfl_xor(p,2); p += __shfl_xor(p,4);
    const float delta = (vv - p)*bet;

    float po = 0.f;
    #pragma unroll
    for (int r=0;r<16;r++) { st[r] += kk[r]*delta; po += qq[r]*st[r]; }
    po += __shfl_xor(po,1); po += __shfl_xor(po,2); po += __shfl_xor(po,4);
    if (rg == 0) ob[(long)s*HH*128] = po;

    #pragma unroll
    for (int r=0;r<16;r++) { kk[r]=nk[r]; qq[r]=nq[r]; }
    vv = nv;
  }
}

// ---------------------------------------------------------------------------
// RMSNorm over DV + (1+nw) + silu(z) gate; writes bf16 for final GEMM
// one block per (b,s,h), 128 threads
// ---------------------------------------------------------------------------
__global__ __launch_bounds__(128) void norm_gate_kernel(
    const float* __restrict__ o, const bf16_t* __restrict__ z,
    const float* __restrict__ nw, bf16_t* __restrict__ og)
{
  const long row = blockIdx.x;      // (b*S+s)*H + h
  const int d = threadIdx.x;
  float x = o[row*128 + d];
  float ss = x*x;
  #pragma unroll
  for (int off=32; off>=1; off>>=1) ss += __shfl_xor(ss, off);
  __shared__ float red[2];
  if ((d & 63) == 0) red[d>>6] = ss;
  __syncthreads();
  float mean = (red[0] + red[1]) * (1.f/128.f);
  float zn = (float)z[row*128 + d];
  float val = x * rsqrtf(mean + 1e-6f) * (1.f + nw[d]) * (zn * (1.f/(1.f+expf(-zn))));
  og[row*128 + d] = (bf16_t)val;
}

// ---------------------------------------------------------------------------
extern "C" void kernel_launch(void* const* d_in, const int* in_sizes, int n_in,
                              void* d_out, int out_size, void* d_ws, size_t ws_size,
                              hipStream_t stream)
{
  const float* hs    = (const float*)d_in[0];
  const float* amask = (const float*)d_in[1];
  const float* Wqkv  = (const float*)d_in[2];
  const float* convw = (const float*)d_in[3];
  const float* convb = (const float*)d_in[4];
  const float* Wz    = (const float*)d_in[5];
  const float* Wb    = (const float*)d_in[6];
  const float* Wa    = (const float*)d_in[7];
  const float* dtb   = (const float*)d_in[8];
  const float* Alog  = (const float*)d_in[9];
  const float* nw    = (const float*)d_in[10];
  const float* Wout  = (const float*)d_in[11];

  char* p = (char*)d_ws;
  auto alloc = [&](size_t bytes) { char* r = p; p += (bytes + 255) & ~(size_t)255; return r; };
  bf16_t* x_bf    = (bf16_t*)alloc((size_t)MM*DD*2);        // 16 MB (og aliases later)
  bf16_t* wqkv_bf = (bf16_t*)alloc((size_t)CONVC*DD*2);     // 24 MB (wout_bf aliases later)
  bf16_t* wz_bf   = (bf16_t*)alloc((size_t)DD*DD*2);        // 8 MB
  bf16_t* mixed   = (bf16_t*)alloc((size_t)MM*CONVC*2);     // 48 MB (obuf aliases later)
  bf16_t* zbuf    = (bf16_t*)alloc((size_t)MM*DD*2);        // 16 MB
  bf16_t* q_t     = (bf16_t*)alloc((size_t)MM*DD*2);        // 16 MB
  bf16_t* k_t     = (bf16_t*)alloc((size_t)MM*DD*2);        // 16 MB
  bf16_t* v_t     = (bf16_t*)alloc((size_t)MM*DD*2);        // 16 MB
  float*  beta_t  = (float*)alloc((size_t)BB*HH*SS*4);
  float*  eg_t    = (float*)alloc((size_t)BB*HH*SS*4);
  size_t need = (size_t)(p - (char*)d_ws);
  if (ws_size < need) return;   // clean fail (diagnosable as absmax=poison)

  // liveness-based aliases
  bf16_t* wout_bf = wqkv_bf;          // cast after GEMM1 consumed wqkv_bf
  float*  obuf    = (float*)mixed;    // rec writes after conv consumed mixed (32MB <= 48MB)
  bf16_t* og      = x_bf;             // written after last read of x_bf (z-GEMM)

  cast_x_kernel<<<2048, 256, 0, stream>>>(hs, amask, x_bf, (long)MM*DD);
  cast_w_kernel<<<2048, 256, 0, stream>>>(Wqkv, wqkv_bf, (long)CONVC*DD);
  cast_w_kernel<<<1024, 256, 0, stream>>>(Wz,   wz_bf,   (long)DD*DD);

  betag_kernel<<<MM, 64, 0, stream>>>(x_bf, Wb, Wa, dtb, Alog, beta_t, eg_t);

  gemm_bt<true><<<dim3(32,48), 256, 0, stream>>>(x_bf, wqkv_bf, mixed, MM, CONVC, DD);
  cast_w_kernel<<<1024, 256, 0, stream>>>(Wout, wout_bf, (long)DD*DD);
  gemm_bt<true><<<dim3(32,16), 256, 0, stream>>>(x_bf, wz_bf,   zbuf,  MM, DD, DD);

  conv_norm_kernel<<<BB*HH*SS, 128, 0, stream>>>(mixed, convw, convb, q_t, k_t, v_t);

  rec_kernel<<<BB*HH*16, 64, 0, stream>>>(q_t, k_t, v_t, beta_t, eg_t, obuf);

  norm_gate_kernel<<<MM*HH, 128, 0, stream>>>(obuf, zbuf, nw, og);

  gemm_bt<false><<<dim3(32,16), 256, 0, stream>>>(og, wout_bf, d_out, MM, DD, DD);
}

// Round 3
// 1358.259 us; speedup vs baseline: 1.3014x; 1.3014x over previous
//
#include <hip/hip_runtime.h>
#include <hip/hip_bf16.h>
#include <math.h>

// Problem constants
#define BB 2
#define SS 2048
#define DD 2048
#define HH 16
#define CONVC 6144
#define MM (BB*SS)   // 4096 tokens

typedef __bf16 bf16_t;
typedef __bf16 bf16x8 __attribute__((ext_vector_type(8)));
typedef __bf16 bf16x4 __attribute__((ext_vector_type(4)));
typedef float  f32x4  __attribute__((ext_vector_type(4)));

#define GLOBAL_AS __attribute__((address_space(1)))
#define LDS_AS    __attribute__((address_space(3)))

// x + x(dpp_perm) — VALU-pipe cross-lane add (no LDS latency)
#define DPP_ADD(x, CTRL) ((x) + __int_as_float(__builtin_amdgcn_update_dpp(0, __float_as_int(x), (CTRL), 0xF, 0xF, true)))

// ---------------------------------------------------------------------------
// Cast kernels
// ---------------------------------------------------------------------------
__global__ __launch_bounds__(256) void cast_x_kernel(
    const float* __restrict__ in, const float* __restrict__ mask,
    bf16_t* __restrict__ out, long n)
{
  long n4 = n >> 2;
  for (long i = (long)blockIdx.x*256 + threadIdx.x; i < n4; i += (long)gridDim.x*256) {
    float4 v = ((const float4*)in)[i];
    float m = mask[(i*4) / DD];
    bf16x4 o4;
    o4[0]=(bf16_t)(v.x*m); o4[1]=(bf16_t)(v.y*m);
    o4[2]=(bf16_t)(v.z*m); o4[3]=(bf16_t)(v.w*m);
    ((bf16x4*)out)[i] = o4;
  }
}

__global__ __launch_bounds__(256) void cast_w_kernel(
    const float* __restrict__ in, bf16_t* __restrict__ out, long n)
{
  long n4 = n >> 2;
  for (long i = (long)blockIdx.x*256 + threadIdx.x; i < n4; i += (long)gridDim.x*256) {
    float4 v = ((const float4*)in)[i];
    bf16x4 o4;
    o4[0]=(bf16_t)v.x; o4[1]=(bf16_t)v.y; o4[2]=(bf16_t)v.z; o4[3]=(bf16_t)v.w;
    ((bf16x4*)out)[i] = o4;
  }
}

// ---------------------------------------------------------------------------
// bf16 MFMA GEMM: C[M,N] = A[M,K] * B[N,K]^T   (m97-style 128x128 tile, BK=32)
// ---------------------------------------------------------------------------
template<bool OUT_BF16>
__global__ __launch_bounds__(256) void gemm_bt(
    const bf16_t* __restrict__ A, const bf16_t* __restrict__ Bm,
    void* __restrict__ Cp, int M, int N, int K)
{
  __shared__ __align__(16) bf16_t lA[128*32];
  __shared__ __align__(16) bf16_t lB[128*32];
  const int t    = threadIdx.x;
  const int lane = t & 63;
  const int w    = t >> 6;       // wave 0..3
  const int wm   = w >> 1, wn = w & 1;
  const int fr   = lane & 15, fq = lane >> 4;
  const long bm  = blockIdx.x, bn = blockIdx.y;

  f32x4 acc[4][4];
  #pragma unroll
  for (int i=0;i<4;i++)
    #pragma unroll
    for (int jj=0;jj<4;jj++) acc[i][jj] = (f32x4){0.f,0.f,0.f,0.f};

  const int r1 = t >> 2;
  const int kb = (t & 3) << 3;
  const bf16_t* a0 = A  + (bm*128 + r1)*(long)K + kb;
  const bf16_t* a1 = a0 + 64*(long)K;
  const bf16_t* b0 = Bm + (bn*128 + r1)*(long)K + kb;
  const bf16_t* b1 = b0 + 64*(long)K;
  bf16_t* lA0 = lA + (w*64)*8;        // wave-uniform LDS bases
  bf16_t* lA1 = lA + (256 + w*64)*8;
  bf16_t* lB0 = lB + (w*64)*8;
  bf16_t* lB1 = lB + (256 + w*64)*8;

  for (int k0 = 0; k0 < K; k0 += 32) {
    __builtin_amdgcn_global_load_lds((const GLOBAL_AS void*)(a0 + k0), (LDS_AS void*)lA0, 16, 0, 0);
    __builtin_amdgcn_global_load_lds((const GLOBAL_AS void*)(a1 + k0), (LDS_AS void*)lA1, 16, 0, 0);
    __builtin_amdgcn_global_load_lds((const GLOBAL_AS void*)(b0 + k0), (LDS_AS void*)lB0, 16, 0, 0);
    __builtin_amdgcn_global_load_lds((const GLOBAL_AS void*)(b1 + k0), (LDS_AS void*)lB1, 16, 0, 0);
    __syncthreads();   // drains vmcnt before reads

    bf16x8 af[4], bfr[4];
    #pragma unroll
    for (int mi=0;mi<4;mi++)
      af[mi] = *(const bf16x8*)(lA + (wm*64 + mi*16 + fr)*32 + fq*8);
    #pragma unroll
    for (int ni=0;ni<4;ni++)
      bfr[ni] = *(const bf16x8*)(lB + (wn*64 + ni*16 + fr)*32 + fq*8);
    #pragma unroll
    for (int mi=0;mi<4;mi++)
      #pragma unroll
      for (int ni=0;ni<4;ni++)
        acc[mi][ni] = __builtin_amdgcn_mfma_f32_16x16x32_bf16(af[mi], bfr[ni], acc[mi][ni], 0, 0, 0);
    __syncthreads();   // protect LDS before next stage
  }

  #pragma unroll
  for (int mi=0;mi<4;mi++) {
    #pragma unroll
    for (int ni=0;ni<4;ni++) {
      long row = bm*128 + wm*64 + mi*16 + fq*4;
      long col = bn*128 + wn*64 + ni*16 + fr;
      #pragma unroll
      for (int r=0;r<4;r++) {
        float v = acc[mi][ni][r];
        if (OUT_BF16) ((bf16_t*)Cp)[(row+r)*(long)N + col] = (bf16_t)v;
        else          ((float*)Cp)[(row+r)*(long)N + col] = v;
      }
    }
  }
}

// ---------------------------------------------------------------------------
// beta / g:  per token, 16 dots with W_b rows and 16 with W_a rows (K=2048)
// ---------------------------------------------------------------------------
__global__ __launch_bounds__(64) void betag_kernel(
    const bf16_t* __restrict__ xbf, const float* __restrict__ W_b,
    const float* __restrict__ W_a, const float* __restrict__ dt_bias,
    const float* __restrict__ A_log, float* __restrict__ beta_t,
    float* __restrict__ eg_t)
{
  const int row  = blockIdx.x;        // token b*S+s
  const int lane = threadIdx.x;
  const int b = row / SS, s = row % SS;

  float xv[32];
  {
    const bf16x8* xr = (const bf16x8*)(xbf + (long)row*DD + lane*32);
    #pragma unroll
    for (int c8=0;c8<4;c8++) {
      bf16x8 v = xr[c8];
      #pragma unroll
      for (int e=0;e<8;e++) xv[c8*8+e] = (float)v[e];
    }
  }

  for (int h=0; h<HH; ++h) {
    const float4* wb4 = (const float4*)(W_b + (long)h*DD + lane*32);
    const float4* wa4 = (const float4*)(W_a + (long)h*DD + lane*32);
    float pb = 0.f, pa = 0.f;
    #pragma unroll
    for (int c4=0;c4<8;c4++) {
      float4 wb = wb4[c4], wa = wa4[c4];
      pb += xv[c4*4+0]*wb.x + xv[c4*4+1]*wb.y + xv[c4*4+2]*wb.z + xv[c4*4+3]*wb.w;
      pa += xv[c4*4+0]*wa.x + xv[c4*4+1]*wa.y + xv[c4*4+2]*wa.z + xv[c4*4+3]*wa.w;
    }
    #pragma unroll
    for (int off=32; off>=1; off>>=1) { pb += __shfl_xor(pb, off); pa += __shfl_xor(pa, off); }
    if (lane == h) {
      beta_t[((long)b*HH + h)*SS + s] = 1.f/(1.f+expf(-pb));
      float tt = pa + dt_bias[h];
      float sp = (tt > 20.f) ? tt : log1pf(expf(tt));
      float g  = -expf(A_log[h]) * sp;
      eg_t[((long)b*HH + h)*SS + s] = expf(g);
    }
  }
}

// ---------------------------------------------------------------------------
// conv(K=4 causal depthwise) + bias + silu + q/k l2norm + transpose to [B,H,S,128]
// ---------------------------------------------------------------------------
__global__ __launch_bounds__(128) void conv_norm_kernel(
    const bf16_t* __restrict__ mixed, const float* __restrict__ cw,
    const float* __restrict__ cb, bf16_t* __restrict__ q_t,
    bf16_t* __restrict__ k_t, bf16_t* __restrict__ v_t)
{
  const int blk = blockIdx.x;           // (b*H+h)*S + s
  const int s = blk & (SS-1);
  const int h = (blk >> 11) & (HH-1);
  const int b = blk >> 15;
  const int d = threadIdx.x;

  const int cq = h*128 + d;
  const int ck = 2048 + cq;
  const int cv = 4096 + cq;
  float aq = cb[cq], ak = cb[ck], av = cb[cv];
  const float* wq = cw + (long)cq*4;
  const float* wk = cw + (long)ck*4;
  const float* wv = cw + (long)cv*4;
  #pragma unroll
  for (int tp=0; tp<4; ++tp) {
    int s2 = s - 3 + tp;
    if (s2 >= 0) {
      const bf16_t* rowp = mixed + ((long)b*SS + s2)*CONVC;
      aq += (float)rowp[cq] * wq[tp];
      ak += (float)rowp[ck] * wk[tp];
      av += (float)rowp[cv] * wv[tp];
    }
  }
  aq = aq * (1.f/(1.f+expf(-aq)));
  ak = ak * (1.f/(1.f+expf(-ak)));
  av = av * (1.f/(1.f+expf(-av)));

  float sq = aq*aq, sk = ak*ak;
  #pragma unroll
  for (int off=32; off>=1; off>>=1) { sq += __shfl_xor(sq, off); sk += __shfl_xor(sk, off); }
  __shared__ float red[4];
  const int wv2 = d >> 6;
  if ((d & 63) == 0) { red[wv2*2] = sq; red[wv2*2+1] = sk; }
  __syncthreads();
  float sumq = red[0] + red[2];
  float sumk = red[1] + red[3];

  const long obase = ((long)(b*HH + h)*SS + s)*128 + d;
  q_t[obase] = (bf16_t)(aq * rsqrtf(sumq + 1e-6f) * 0.08838834764831845f);  // * DK^-0.5
  k_t[obase] = (bf16_t)(ak * rsqrtf(sumk + 1e-6f));
  v_t[obase] = (bf16_t)av;
}

// ---------------------------------------------------------------------------
// gated delta rule recurrence. One wave per (b,h, 8-column group).
// lane = cl*8+rg : column j = cg*8+cl, rows i = rg*16..+16 held in VGPRs.
// DPP reduction over rg (xor1, xor2, quad-pair) — no LDS-pipe shuffles.
// ---------------------------------------------------------------------------
__global__ __launch_bounds__(64) void rec_kernel(
    const bf16_t* __restrict__ q_t, const bf16_t* __restrict__ k_t,
    const bf16_t* __restrict__ v_t, const float* __restrict__ beta_t,
    const float* __restrict__ eg_t, float* __restrict__ o)
{
  // XCD swizzle: 512 blocks = 8 XCDs * 64; keep all 16 cg-waves of a bh on one XCD
  const int bid  = blockIdx.x;
  const int blk  = (bid & 7)*64 + (bid >> 3);
  const int cg   = blk & 15;
  const int bh   = blk >> 4;
  const int lane = threadIdx.x;
  const int cl   = lane >> 3;
  const int rg   = lane & 7;
  const int j    = cg*8 + cl;
  const int i0   = rg*16;
  const int b    = bh >> 4, h = bh & 15;

  const bf16_t* qb  = q_t + (long)bh*SS*128 + i0;
  const bf16_t* kb  = k_t + (long)bh*SS*128 + i0;
  const bf16_t* vb  = v_t + (long)bh*SS*128 + j;
  const float* egb = eg_t  + (long)bh*SS;
  const float* btb = beta_t + (long)bh*SS;
  float* ob = o + (long)b*SS*HH*128 + h*128 + j;

  float st[16];
  #pragma unroll
  for (int r=0;r<16;r++) st[r] = 0.f;

  bf16x8 Ak0, Ak1, Aq0, Aq1; float Av;
  bf16x8 Bk0, Bk1, Bq0, Bq1; float Bv;
  Ak0 = *(const bf16x8*)(kb);
  Ak1 = *(const bf16x8*)(kb + 8);
  Aq0 = *(const bf16x8*)(qb);
  Aq1 = *(const bf16x8*)(qb + 8);
  Av  = (float)vb[0];

#define REC_STEP(S, Ck0, Ck1, Cq0, Cq1, Cv, Nk0, Nk1, Nq0, Nq1, Nv)            \
  {                                                                            \
    const long sn = ((S)+1 < SS) ? (S)+1 : (S);                                \
    Nk0 = *(const bf16x8*)(kb + sn*128);                                       \
    Nk1 = *(const bf16x8*)(kb + sn*128 + 8);                                   \
    Nq0 = *(const bf16x8*)(qb + sn*128);                                       \
    Nq1 = *(const bf16x8*)(qb + sn*128 + 8);                                   \
    Nv  = (float)vb[sn*128];                                                   \
    const float eg  = egb[(S)];                                                \
    const float bet = btb[(S)];                                                \
    float kk[16], qq[16];                                                      \
    _Pragma("unroll")                                                          \
    for (int e=0;e<8;e++) {                                                    \
      kk[e]=(float)Ck0[e]; kk[8+e]=(float)Ck1[e];                              \
      qq[e]=(float)Cq0[e]; qq[8+e]=(float)Cq1[e];                              \
    }                                                                          \
    float p0=0.f,p1=0.f,p2=0.f,p3=0.f;                                         \
    _Pragma("unroll")                                                          \
    for (int r=0;r<4;r++) {                                                    \
      p0 += kk[r]*st[r];      p1 += kk[4+r]*st[4+r];                           \
      p2 += kk[8+r]*st[8+r];  p3 += kk[12+r]*st[12+r];                         \
    }                                                                          \
    float p = (p0+p1)+(p2+p3);                                                 \
    p = DPP_ADD(p, 0xB1);                                                      \
    p = DPP_ADD(p, 0x4E);                                                      \
    p = DPP_ADD(p, 0x141);                                                     \
    const float delta = (Cv - p*eg)*bet;                                       \
    float o0=0.f,o1=0.f,o2=0.f,o3=0.f;                                         \
    _Pragma("unroll")                                                          \
    for (int r=0;r<4;r++) {                                                    \
      st[r]    = fmaf(st[r],    eg, kk[r]*delta);                              \
      st[4+r]  = fmaf(st[4+r],  eg, kk[4+r]*delta);                            \
      st[8+r]  = fmaf(st[8+r],  eg, kk[8+r]*delta);                            \
      st[12+r] = fmaf(st[12+r], eg, kk[12+r]*delta);                           \
      o0 += qq[r]*st[r];      o1 += qq[4+r]*st[4+r];                           \
      o2 += qq[8+r]*st[8+r];  o3 += qq[12+r]*st[12+r];                         \
    }                                                                          \
    float po = (o0+o1)+(o2+o3);                                                \
    po = DPP_ADD(po, 0xB1);                                                    \
    po = DPP_ADD(po, 0x4E);                                                    \
    po = DPP_ADD(po, 0x141);                                                   \
    if (rg == 0) ob[(long)(S)*HH*128] = po;                                    \
  }

  for (int s=0; s<SS; s+=2) {
    REC_STEP(s,   Ak0,Ak1,Aq0,Aq1,Av,  Bk0,Bk1,Bq0,Bq1,Bv);
    REC_STEP(s+1, Bk0,Bk1,Bq0,Bq1,Bv,  Ak0,Ak1,Aq0,Aq1,Av);
  }
#undef REC_STEP
}

// ---------------------------------------------------------------------------
// RMSNorm over DV + (1+nw) + silu(z) gate; writes bf16 for final GEMM
// ---------------------------------------------------------------------------
__global__ __launch_bounds__(128) void norm_gate_kernel(
    const float* __restrict__ o, const bf16_t* __restrict__ z,
    const float* __restrict__ nw, bf16_t* __restrict__ og)
{
  const long row = blockIdx.x;      // (b*S+s)*H + h
  const int d = threadIdx.x;
  float x = o[row*128 + d];
  float ss = x*x;
  #pragma unroll
  for (int off=32; off>=1; off>>=1) ss += __shfl_xor(ss, off);
  __shared__ float red[2];
  if ((d & 63) == 0) red[d>>6] = ss;
  __syncthreads();
  float mean = (red[0] + red[1]) * (1.f/128.f);
  float zn = (float)z[row*128 + d];
  float val = x * rsqrtf(mean + 1e-6f) * (1.f + nw[d]) * (zn * (1.f/(1.f+expf(-zn))));
  og[row*128 + d] = (bf16_t)val;
}

// ---------------------------------------------------------------------------
extern "C" void kernel_launch(void* const* d_in, const int* in_sizes, int n_in,
                              void* d_out, int out_size, void* d_ws, size_t ws_size,
                              hipStream_t stream)
{
  const float* hs    = (const float*)d_in[0];
  const float* amask = (const float*)d_in[1];
  const float* Wqkv  = (const float*)d_in[2];
  const float* convw = (const float*)d_in[3];
  const float* convb = (const float*)d_in[4];
  const float* Wz    = (const float*)d_in[5];
  const float* Wb    = (const float*)d_in[6];
  const float* Wa    = (const float*)d_in[7];
  const float* dtb   = (const float*)d_in[8];
  const float* Alog  = (const float*)d_in[9];
  const float* nw    = (const float*)d_in[10];
  const float* Wout  = (const float*)d_in[11];

  char* p = (char*)d_ws;
  auto alloc = [&](size_t bytes) { char* r = p; p += (bytes + 255) & ~(size_t)255; return r; };
  bf16_t* x_bf    = (bf16_t*)alloc((size_t)MM*DD*2);        // 16 MB (og aliases later)
  bf16_t* wqkv_bf = (bf16_t*)alloc((size_t)CONVC*DD*2);     // 24 MB (wout_bf aliases later)
  bf16_t* wz_bf   = (bf16_t*)alloc((size_t)DD*DD*2);        // 8 MB
  bf16_t* mixed   = (bf16_t*)alloc((size_t)MM*CONVC*2);     // 48 MB (obuf aliases later)
  bf16_t* zbuf    = (bf16_t*)alloc((size_t)MM*DD*2);        // 16 MB
  bf16_t* q_t     = (bf16_t*)alloc((size_t)MM*DD*2);        // 16 MB
  bf16_t* k_t     = (bf16_t*)alloc((size_t)MM*DD*2);        // 16 MB
  bf16_t* v_t     = (bf16_t*)alloc((size_t)MM*DD*2);        // 16 MB
  float*  beta_t  = (float*)alloc((size_t)BB*HH*SS*4);
  float*  eg_t    = (float*)alloc((size_t)BB*HH*SS*4);
  size_t need = (size_t)(p - (char*)d_ws);
  if (ws_size < need) return;   // clean fail (diagnosable as absmax=poison)

  // liveness-based aliases
  bf16_t* wout_bf = wqkv_bf;          // cast after GEMM1 consumed wqkv_bf
  float*  obuf    = (float*)mixed;    // rec writes after conv consumed mixed (32MB <= 48MB)
  bf16_t* og      = x_bf;             // written after last read of x_bf (z-GEMM)

  cast_x_kernel<<<2048, 256, 0, stream>>>(hs, amask, x_bf, (long)MM*DD);
  cast_w_kernel<<<2048, 256, 0, stream>>>(Wqkv, wqkv_bf, (long)CONVC*DD);
  cast_w_kernel<<<1024, 256, 0, stream>>>(Wz,   wz_bf,   (long)DD*DD);

  betag_kernel<<<MM, 64, 0, stream>>>(x_bf, Wb, Wa, dtb, Alog, beta_t, eg_t);

  gemm_bt<true><<<dim3(32,48), 256, 0, stream>>>(x_bf, wqkv_bf, mixed, MM, CONVC, DD);
  cast_w_kernel<<<1024, 256, 0, stream>>>(Wout, wout_bf, (long)DD*DD);
  gemm_bt<true><<<dim3(32,16), 256, 0, stream>>>(x_bf, wz_bf,   zbuf,  MM, DD, DD);

  conv_norm_kernel<<<BB*HH*SS, 128, 0, stream>>>(mixed, convw, convb, q_t, k_t, v_t);

  rec_kernel<<<BB*HH*16, 64, 0, stream>>>(q_t, k_t, v_t, beta_t, eg_t, obuf);

  norm_gate_kernel<<<MM*HH, 128, 0, stream>>>(obuf, zbuf, nw, og);

  gemm_bt<false><<<dim3(32,16), 256, 0, stream>>>(og, wout_bf, d_out, MM, DD, DD);
}

// Round 4
// 1068.729 us; speedup vs baseline: 1.6539x; 1.2709x over previous
//
#include <hip/hip_runtime.h>
#include <hip/hip_bf16.h>
#include <math.h>

// Problem constants
#define BB 2
#define SS 2048
#define DD 2048
#define HH 16
#define CONVC 6144
#define MM (BB*SS)   // 4096 tokens

typedef __bf16 bf16_t;
typedef __bf16 bf16x8 __attribute__((ext_vector_type(8)));
typedef __bf16 bf16x4 __attribute__((ext_vector_type(4)));
typedef float  f32x4  __attribute__((ext_vector_type(4)));
typedef float  f32x2  __attribute__((ext_vector_type(2)));
typedef unsigned int u32x4 __attribute__((ext_vector_type(4)));

#define GLOBAL_AS __attribute__((address_space(1)))
#define LDS_AS    __attribute__((address_space(3)))

// x + x(dpp_perm) — VALU-pipe cross-lane add (no LDS latency)
#define DPP_ADD(x, CTRL) ((x) + __int_as_float(__builtin_amdgcn_update_dpp(0, __float_as_int(x), (CTRL), 0xF, 0xF, true)))

// ---------------------------------------------------------------------------
// Cast kernels
// ---------------------------------------------------------------------------
__global__ __launch_bounds__(256) void cast_x_kernel(
    const float* __restrict__ in, const float* __restrict__ mask,
    bf16_t* __restrict__ out, long n)
{
  long n4 = n >> 2;
  for (long i = (long)blockIdx.x*256 + threadIdx.x; i < n4; i += (long)gridDim.x*256) {
    float4 v = ((const float4*)in)[i];
    float m = mask[(i*4) / DD];
    bf16x4 o4;
    o4[0]=(bf16_t)(v.x*m); o4[1]=(bf16_t)(v.y*m);
    o4[2]=(bf16_t)(v.z*m); o4[3]=(bf16_t)(v.w*m);
    ((bf16x4*)out)[i] = o4;
  }
}

__global__ __launch_bounds__(256) void cast_w_kernel(
    const float* __restrict__ in, bf16_t* __restrict__ out, long n)
{
  long n4 = n >> 2;
  for (long i = (long)blockIdx.x*256 + threadIdx.x; i < n4; i += (long)gridDim.x*256) {
    float4 v = ((const float4*)in)[i];
    bf16x4 o4;
    o4[0]=(bf16_t)v.x; o4[1]=(bf16_t)v.y; o4[2]=(bf16_t)v.z; o4[3]=(bf16_t)v.w;
    ((bf16x4*)out)[i] = o4;
  }
}

// ---------------------------------------------------------------------------
// bf16 MFMA GEMM: C[M,N] = A[M,K] * B[N,K]^T   (m97-style 128x128 tile, BK=32)
// ---------------------------------------------------------------------------
template<bool OUT_BF16>
__global__ __launch_bounds__(256) void gemm_bt(
    const bf16_t* __restrict__ A, const bf16_t* __restrict__ Bm,
    void* __restrict__ Cp, int M, int N, int K)
{
  __shared__ __align__(16) bf16_t lA[128*32];
  __shared__ __align__(16) bf16_t lB[128*32];
  const int t    = threadIdx.x;
  const int lane = t & 63;
  const int w    = t >> 6;       // wave 0..3
  const int wm   = w >> 1, wn = w & 1;
  const int fr   = lane & 15, fq = lane >> 4;
  const long bm  = blockIdx.x, bn = blockIdx.y;

  f32x4 acc[4][4];
  #pragma unroll
  for (int i=0;i<4;i++)
    #pragma unroll
    for (int jj=0;jj<4;jj++) acc[i][jj] = (f32x4){0.f,0.f,0.f,0.f};

  const int r1 = t >> 2;
  const int kb = (t & 3) << 3;
  const bf16_t* a0 = A  + (bm*128 + r1)*(long)K + kb;
  const bf16_t* a1 = a0 + 64*(long)K;
  const bf16_t* b0 = Bm + (bn*128 + r1)*(long)K + kb;
  const bf16_t* b1 = b0 + 64*(long)K;
  bf16_t* lA0 = lA + (w*64)*8;        // wave-uniform LDS bases
  bf16_t* lA1 = lA + (256 + w*64)*8;
  bf16_t* lB0 = lB + (w*64)*8;
  bf16_t* lB1 = lB + (256 + w*64)*8;

  for (int k0 = 0; k0 < K; k0 += 32) {
    __builtin_amdgcn_global_load_lds((const GLOBAL_AS void*)(a0 + k0), (LDS_AS void*)lA0, 16, 0, 0);
    __builtin_amdgcn_global_load_lds((const GLOBAL_AS void*)(a1 + k0), (LDS_AS void*)lA1, 16, 0, 0);
    __builtin_amdgcn_global_load_lds((const GLOBAL_AS void*)(b0 + k0), (LDS_AS void*)lB0, 16, 0, 0);
    __builtin_amdgcn_global_load_lds((const GLOBAL_AS void*)(b1 + k0), (LDS_AS void*)lB1, 16, 0, 0);
    __syncthreads();   // drains vmcnt before reads

    bf16x8 af[4], bfr[4];
    #pragma unroll
    for (int mi=0;mi<4;mi++)
      af[mi] = *(const bf16x8*)(lA + (wm*64 + mi*16 + fr)*32 + fq*8);
    #pragma unroll
    for (int ni=0;ni<4;ni++)
      bfr[ni] = *(const bf16x8*)(lB + (wn*64 + ni*16 + fr)*32 + fq*8);
    #pragma unroll
    for (int mi=0;mi<4;mi++)
      #pragma unroll
      for (int ni=0;ni<4;ni++)
        acc[mi][ni] = __builtin_amdgcn_mfma_f32_16x16x32_bf16(af[mi], bfr[ni], acc[mi][ni], 0, 0, 0);
    __syncthreads();   // protect LDS before next stage
  }

  #pragma unroll
  for (int mi=0;mi<4;mi++) {
    #pragma unroll
    for (int ni=0;ni<4;ni++) {
      long row = bm*128 + wm*64 + mi*16 + fq*4;
      long col = bn*128 + wn*64 + ni*16 + fr;
      #pragma unroll
      for (int r=0;r<4;r++) {
        float v = acc[mi][ni][r];
        if (OUT_BF16) ((bf16_t*)Cp)[(row+r)*(long)N + col] = (bf16_t)v;
        else          ((float*)Cp)[(row+r)*(long)N + col] = v;
      }
    }
  }
}

// ---------------------------------------------------------------------------
// beta / g:  per token, 16 dots with W_b rows and 16 with W_a rows (K=2048)
// writes gb_t[bh][s] = {exp(g), beta}
// ---------------------------------------------------------------------------
__global__ __launch_bounds__(64) void betag_kernel(
    const bf16_t* __restrict__ xbf, const float* __restrict__ W_b,
    const float* __restrict__ W_a, const float* __restrict__ dt_bias,
    const float* __restrict__ A_log, float2* __restrict__ gb_t)
{
  const int row  = blockIdx.x;        // token b*S+s
  const int lane = threadIdx.x;
  const int b = row / SS, s = row % SS;

  float xv[32];
  {
    const bf16x8* xr = (const bf16x8*)(xbf + (long)row*DD + lane*32);
    #pragma unroll
    for (int c8=0;c8<4;c8++) {
      bf16x8 v = xr[c8];
      #pragma unroll
      for (int e=0;e<8;e++) xv[c8*8+e] = (float)v[e];
    }
  }

  for (int h=0; h<HH; ++h) {
    const float4* wb4 = (const float4*)(W_b + (long)h*DD + lane*32);
    const float4* wa4 = (const float4*)(W_a + (long)h*DD + lane*32);
    float pb = 0.f, pa = 0.f;
    #pragma unroll
    for (int c4=0;c4<8;c4++) {
      float4 wb = wb4[c4], wa = wa4[c4];
      pb += xv[c4*4+0]*wb.x + xv[c4*4+1]*wb.y + xv[c4*4+2]*wb.z + xv[c4*4+3]*wb.w;
      pa += xv[c4*4+0]*wa.x + xv[c4*4+1]*wa.y + xv[c4*4+2]*wa.z + xv[c4*4+3]*wa.w;
    }
    #pragma unroll
    for (int off=32; off>=1; off>>=1) { pb += __shfl_xor(pb, off); pa += __shfl_xor(pa, off); }
    if (lane == h) {
      float beta = 1.f/(1.f+expf(-pb));
      float tt = pa + dt_bias[h];
      float sp = (tt > 20.f) ? tt : log1pf(expf(tt));
      float g  = -expf(A_log[h]) * sp;
      gb_t[((long)b*HH + h)*SS + s] = make_float2(expf(g), beta);
    }
  }
}

// ---------------------------------------------------------------------------
// conv(K=4 causal depthwise) + bias + silu + q/k l2norm + transpose to [B,H,S,128]
// ---------------------------------------------------------------------------
__global__ __launch_bounds__(128) void conv_norm_kernel(
    const bf16_t* __restrict__ mixed, const float* __restrict__ cw,
    const float* __restrict__ cb, bf16_t* __restrict__ q_t,
    bf16_t* __restrict__ k_t, bf16_t* __restrict__ v_t)
{
  const int blk = blockIdx.x;           // (b*H+h)*S + s
  const int s = blk & (SS-1);
  const int h = (blk >> 11) & (HH-1);
  const int b = blk >> 15;
  const int d = threadIdx.x;

  const int cq = h*128 + d;
  const int ck = 2048 + cq;
  const int cv = 4096 + cq;
  float aq = cb[cq], ak = cb[ck], av = cb[cv];
  const float* wq = cw + (long)cq*4;
  const float* wk = cw + (long)ck*4;
  const float* wv = cw + (long)cv*4;
  #pragma unroll
  for (int tp=0; tp<4; ++tp) {
    int s2 = s - 3 + tp;
    if (s2 >= 0) {
      const bf16_t* rowp = mixed + ((long)b*SS + s2)*CONVC;
      aq += (float)rowp[cq] * wq[tp];
      ak += (float)rowp[ck] * wk[tp];
      av += (float)rowp[cv] * wv[tp];
    }
  }
  aq = aq * (1.f/(1.f+expf(-aq)));
  ak = ak * (1.f/(1.f+expf(-ak)));
  av = av * (1.f/(1.f+expf(-av)));

  float sq = aq*aq, sk = ak*ak;
  #pragma unroll
  for (int off=32; off>=1; off>>=1) { sq += __shfl_xor(sq, off); sk += __shfl_xor(sk, off); }
  __shared__ float red[4];
  const int wv2 = d >> 6;
  if ((d & 63) == 0) { red[wv2*2] = sq; red[wv2*2+1] = sk; }
  __syncthreads();
  float sumq = red[0] + red[2];
  float sumk = red[1] + red[3];

  const long obase = ((long)(b*HH + h)*SS + s)*128 + d;
  q_t[obase] = (bf16_t)(aq * rsqrtf(sumq + 1e-6f) * 0.08838834764831845f);  // * DK^-0.5
  k_t[obase] = (bf16_t)(ak * rsqrtf(sumk + 1e-6f));
  v_t[obase] = (bf16_t)av;
}

// ---------------------------------------------------------------------------
// gated delta rule recurrence. One wave per (b,h, 8-column group).
// lane = cl*8+rg : column j = cg*8+cl, rows i = rg*16..+16 (as 8 f32x2 pairs).
// Distance-2 software pipeline: ALL per-step inputs (k,q,v,gb) prefetched.
// Packed f32x2 math -> v_pk_fma_f32. DPP reduction over rg.
// ---------------------------------------------------------------------------
__global__ __launch_bounds__(64) void rec_kernel(
    const bf16_t* __restrict__ q_t, const bf16_t* __restrict__ k_t,
    const bf16_t* __restrict__ v_t, const float2* __restrict__ gb_t,
    float* __restrict__ o)
{
  // XCD swizzle: 512 blocks = 8 XCDs * 64; keep all 16 cg-waves of a bh on one XCD
  const int bid  = blockIdx.x;
  const int blk  = (bid & 7)*64 + (bid >> 3);
  const int cg   = blk & 15;
  const int bh   = blk >> 4;
  const int lane = threadIdx.x;
  const int cl   = lane >> 3;
  const int rg   = lane & 7;
  const int j    = cg*8 + cl;
  const int i0   = rg*16;
  const int b    = bh >> 4, h = bh & 15;

  const bf16_t* qb  = q_t + (long)bh*SS*128 + i0;
  const bf16_t* kb  = k_t + (long)bh*SS*128 + i0;
  const bf16_t* vb  = v_t + (long)bh*SS*128 + j;
  const float2* gbb = gb_t + (long)bh*SS;
  float* ob = o + (long)b*SS*HH*128 + h*128 + j;

  f32x2 st[8];
  #pragma unroll
  for (int r=0;r<8;r++) st[r] = (f32x2){0.f,0.f};

  bf16x8 Ak0, Ak1, Aq0, Aq1; float Av; float2 Agb;
  bf16x8 Bk0, Bk1, Bq0, Bq1; float Bv; float2 Bgb;
  Ak0 = *(const bf16x8*)(kb);
  Ak1 = *(const bf16x8*)(kb + 8);
  Aq0 = *(const bf16x8*)(qb);
  Aq1 = *(const bf16x8*)(qb + 8);
  Av  = (float)vb[0];
  Agb = gbb[0];
  Bk0 = *(const bf16x8*)(kb + 128);
  Bk1 = *(const bf16x8*)(kb + 128 + 8);
  Bq0 = *(const bf16x8*)(qb + 128);
  Bq1 = *(const bf16x8*)(qb + 128 + 8);
  Bv  = (float)vb[128];
  Bgb = gbb[1];

  // bf16 pair (one u32) -> f32x2 via shift/mask (1 op/elem, no cvt chain)
#define CVT_PAIR(dst, w) { (dst)[0] = __int_as_float((int)((w) << 16)); \
                           (dst)[1] = __int_as_float((int)((w) & 0xFFFF0000u)); }

#define REC_STEP(S, Ck0, Ck1, Cq0, Cq1, Cv, Cgb, Nk0, Nk1, Nq0, Nq1, Nv, Ngb)  \
  {                                                                            \
    f32x2 kk[8], qq[8];                                                        \
    {                                                                          \
      u32x4 w0 = __builtin_bit_cast(u32x4, Ck0);                               \
      u32x4 w1 = __builtin_bit_cast(u32x4, Ck1);                               \
      u32x4 y0 = __builtin_bit_cast(u32x4, Cq0);                               \
      u32x4 y1 = __builtin_bit_cast(u32x4, Cq1);                               \
      _Pragma("unroll")                                                        \
      for (int e=0;e<4;e++) {                                                  \
        CVT_PAIR(kk[e],   w0[e]); CVT_PAIR(kk[4+e], w1[e]);                    \
        CVT_PAIR(qq[e],   y0[e]); CVT_PAIR(qq[4+e], y1[e]);                    \
      }                                                                        \
    }                                                                          \
    const float eg  = Cgb.x;                                                   \
    const float bet = Cgb.y;                                                   \
    const float cv  = Cv;                                                      \
    /* reissue loads into this buffer for step S+2 (distance-2 prefetch) */    \
    {                                                                          \
      const long sn = ((S)+2 < SS) ? (S)+2 : (SS-1);                           \
      Nk0 = *(const bf16x8*)(kb + sn*128);                                     \
      Nk1 = *(const bf16x8*)(kb + sn*128 + 8);                                 \
      Nq0 = *(const bf16x8*)(qb + sn*128);                                     \
      Nq1 = *(const bf16x8*)(qb + sn*128 + 8);                                 \
      Nv  = (float)vb[sn*128];                                                 \
      Ngb = gbb[sn];                                                           \
    }                                                                          \
    f32x2 p2 = kk[0]*st[0];                                                    \
    _Pragma("unroll")                                                          \
    for (int r=1;r<8;r++) p2 += kk[r]*st[r];                                   \
    float p = p2[0] + p2[1];                                                   \
    p = DPP_ADD(p, 0xB1);                                                      \
    p = DPP_ADD(p, 0x4E);                                                      \
    p = DPP_ADD(p, 0x141);                                                     \
    const float delta = (cv - p*eg)*bet;                                       \
    const f32x2 d2  = (f32x2){delta, delta};                                   \
    const f32x2 eg2 = (f32x2){eg, eg};                                         \
    f32x2 po2 = (f32x2){0.f,0.f};                                              \
    _Pragma("unroll")                                                          \
    for (int r=0;r<8;r++) {                                                    \
      st[r] = st[r]*eg2 + kk[r]*d2;                                            \
      po2  += qq[r]*st[r];                                                     \
    }                                                                          \
    float po = po2[0] + po2[1];                                                \
    po = DPP_ADD(po, 0xB1);                                                    \
    po = DPP_ADD(po, 0x4E);                                                    \
    po = DPP_ADD(po, 0x141);                                                   \
    if (rg == 0) ob[(long)(S)*HH*128] = po;                                    \
  }

  for (int s=0; s<SS; s+=2) {
    REC_STEP(s,   Ak0,Ak1,Aq0,Aq1,Av,Agb,  Ak0,Ak1,Aq0,Aq1,Av,Agb);
    REC_STEP(s+1, Bk0,Bk1,Bq0,Bq1,Bv,Bgb,  Bk0,Bk1,Bq0,Bq1,Bv,Bgb);
  }
#undef REC_STEP
#undef CVT_PAIR
}

// ---------------------------------------------------------------------------
// RMSNorm over DV + (1+nw) + silu(z) gate; writes bf16 for final GEMM
// ---------------------------------------------------------------------------
__global__ __launch_bounds__(128) void norm_gate_kernel(
    const float* __restrict__ o, const bf16_t* __restrict__ z,
    const float* __restrict__ nw, bf16_t* __restrict__ og)
{
  const long row = blockIdx.x;      // (b*S+s)*H + h
  const int d = threadIdx.x;
  float x = o[row*128 + d];
  float ss = x*x;
  #pragma unroll
  for (int off=32; off>=1; off>>=1) ss += __shfl_xor(ss, off);
  __shared__ float red[2];
  if ((d & 63) == 0) red[d>>6] = ss;
  __syncthreads();
  float mean = (red[0] + red[1]) * (1.f/128.f);
  float zn = (float)z[row*128 + d];
  float val = x * rsqrtf(mean + 1e-6f) * (1.f + nw[d]) * (zn * (1.f/(1.f+expf(-zn))));
  og[row*128 + d] = (bf16_t)val;
}

// ---------------------------------------------------------------------------
extern "C" void kernel_launch(void* const* d_in, const int* in_sizes, int n_in,
                              void* d_out, int out_size, void* d_ws, size_t ws_size,
                              hipStream_t stream)
{
  const float* hs    = (const float*)d_in[0];
  const float* amask = (const float*)d_in[1];
  const float* Wqkv  = (const float*)d_in[2];
  const float* convw = (const float*)d_in[3];
  const float* convb = (const float*)d_in[4];
  const float* Wz    = (const float*)d_in[5];
  const float* Wb    = (const float*)d_in[6];
  const float* Wa    = (const float*)d_in[7];
  const float* dtb   = (const float*)d_in[8];
  const float* Alog  = (const float*)d_in[9];
  const float* nw    = (const float*)d_in[10];
  const float* Wout  = (const float*)d_in[11];

  char* p = (char*)d_ws;
  auto alloc = [&](size_t bytes) { char* r = p; p += (bytes + 255) & ~(size_t)255; return r; };
  bf16_t* x_bf    = (bf16_t*)alloc((size_t)MM*DD*2);        // 16 MB (og aliases later)
  bf16_t* wqkv_bf = (bf16_t*)alloc((size_t)CONVC*DD*2);     // 24 MB (wout_bf aliases later)
  bf16_t* wz_bf   = (bf16_t*)alloc((size_t)DD*DD*2);        // 8 MB
  bf16_t* mixed   = (bf16_t*)alloc((size_t)MM*CONVC*2);     // 48 MB (obuf aliases later)
  bf16_t* zbuf    = (bf16_t*)alloc((size_t)MM*DD*2);        // 16 MB
  bf16_t* q_t     = (bf16_t*)alloc((size_t)MM*DD*2);        // 16 MB
  bf16_t* k_t     = (bf16_t*)alloc((size_t)MM*DD*2);        // 16 MB
  bf16_t* v_t     = (bf16_t*)alloc((size_t)MM*DD*2);        // 16 MB
  float2* gb_t    = (float2*)alloc((size_t)BB*HH*SS*8);
  size_t need = (size_t)(p - (char*)d_ws);
  if (ws_size < need) return;   // clean fail (diagnosable as absmax=poison)

  // liveness-based aliases
  bf16_t* wout_bf = wqkv_bf;          // cast after GEMM1 consumed wqkv_bf
  float*  obuf    = (float*)mixed;    // rec writes after conv consumed mixed (32MB <= 48MB)
  bf16_t* og      = x_bf;             // written after last read of x_bf (z-GEMM)

  cast_x_kernel<<<2048, 256, 0, stream>>>(hs, amask, x_bf, (long)MM*DD);
  cast_w_kernel<<<2048, 256, 0, stream>>>(Wqkv, wqkv_bf, (long)CONVC*DD);
  cast_w_kernel<<<1024, 256, 0, stream>>>(Wz,   wz_bf,   (long)DD*DD);

  betag_kernel<<<MM, 64, 0, stream>>>(x_bf, Wb, Wa, dtb, Alog, gb_t);

  gemm_bt<true><<<dim3(32,48), 256, 0, stream>>>(x_bf, wqkv_bf, mixed, MM, CONVC, DD);
  cast_w_kernel<<<1024, 256, 0, stream>>>(Wout, wout_bf, (long)DD*DD);
  gemm_bt<true><<<dim3(32,16), 256, 0, stream>>>(x_bf, wz_bf,   zbuf,  MM, DD, DD);

  conv_norm_kernel<<<BB*HH*SS, 128, 0, stream>>>(mixed, convw, convb, q_t, k_t, v_t);

  rec_kernel<<<BB*HH*16, 64, 0, stream>>>(q_t, k_t, v_t, gb_t, obuf);

  norm_gate_kernel<<<MM*HH, 128, 0, stream>>>(obuf, zbuf, nw, og);

  gemm_bt<false><<<dim3(32,16), 256, 0, stream>>>(og, wout_bf, d_out, MM, DD, DD);
}

// Round 5
// 969.302 us; speedup vs baseline: 1.8236x; 1.1026x over previous
//
#include <hip/hip_runtime.h>
#include <hip/hip_bf16.h>
#include <math.h>

// Problem constants
#define BB 2
#define SS 2048
#define DD 2048
#define HH 16
#define CONVC 6144
#define MM (BB*SS)   // 4096 tokens

typedef __bf16 bf16_t;
typedef __bf16 bf16x8 __attribute__((ext_vector_type(8)));
typedef __bf16 bf16x4 __attribute__((ext_vector_type(4)));
typedef float  f32x4  __attribute__((ext_vector_type(4)));
typedef float  f32x2  __attribute__((ext_vector_type(2)));
typedef unsigned int u32x4 __attribute__((ext_vector_type(4)));

#define GLOBAL_AS __attribute__((address_space(1)))
#define LDS_AS    __attribute__((address_space(3)))

// x + x(dpp_perm) — VALU-pipe cross-lane add (no LDS latency)
#define DPP_ADD(x, CTRL) ((x) + __int_as_float(__builtin_amdgcn_update_dpp(0, __float_as_int(x), (CTRL), 0xF, 0xF, true)))

// ---------------------------------------------------------------------------
// Cast kernels
// ---------------------------------------------------------------------------
__global__ __launch_bounds__(256) void cast_x_kernel(
    const float* __restrict__ in, const float* __restrict__ mask,
    bf16_t* __restrict__ out, long n)
{
  long n4 = n >> 2;
  for (long i = (long)blockIdx.x*256 + threadIdx.x; i < n4; i += (long)gridDim.x*256) {
    float4 v = ((const float4*)in)[i];
    float m = mask[(i*4) / DD];
    bf16x4 o4;
    o4[0]=(bf16_t)(v.x*m); o4[1]=(bf16_t)(v.y*m);
    o4[2]=(bf16_t)(v.z*m); o4[3]=(bf16_t)(v.w*m);
    ((bf16x4*)out)[i] = o4;
  }
}

__global__ __launch_bounds__(256) void cast_w_kernel(
    const float* __restrict__ in, bf16_t* __restrict__ out, long n)
{
  long n4 = n >> 2;
  for (long i = (long)blockIdx.x*256 + threadIdx.x; i < n4; i += (long)gridDim.x*256) {
    float4 v = ((const float4*)in)[i];
    bf16x4 o4;
    o4[0]=(bf16_t)v.x; o4[1]=(bf16_t)v.y; o4[2]=(bf16_t)v.z; o4[3]=(bf16_t)v.w;
    ((bf16x4*)out)[i] = o4;
  }
}

// ---------------------------------------------------------------------------
// bf16 MFMA GEMM: C[M,N] = A[M,K] * B[N,K]^T   (m97-style 128x128 tile, BK=32)
// ---------------------------------------------------------------------------
template<bool OUT_BF16>
__global__ __launch_bounds__(256) void gemm_bt(
    const bf16_t* __restrict__ A, const bf16_t* __restrict__ Bm,
    void* __restrict__ Cp, int M, int N, int K)
{
  __shared__ __align__(16) bf16_t lA[128*32];
  __shared__ __align__(16) bf16_t lB[128*32];
  const int t    = threadIdx.x;
  const int lane = t & 63;
  const int w    = t >> 6;       // wave 0..3
  const int wm   = w >> 1, wn = w & 1;
  const int fr   = lane & 15, fq = lane >> 4;
  const long bm  = blockIdx.x, bn = blockIdx.y;

  f32x4 acc[4][4];
  #pragma unroll
  for (int i=0;i<4;i++)
    #pragma unroll
    for (int jj=0;jj<4;jj++) acc[i][jj] = (f32x4){0.f,0.f,0.f,0.f};

  const int r1 = t >> 2;
  const int kb = (t & 3) << 3;
  const bf16_t* a0 = A  + (bm*128 + r1)*(long)K + kb;
  const bf16_t* a1 = a0 + 64*(long)K;
  const bf16_t* b0 = Bm + (bn*128 + r1)*(long)K + kb;
  const bf16_t* b1 = b0 + 64*(long)K;
  bf16_t* lA0 = lA + (w*64)*8;        // wave-uniform LDS bases
  bf16_t* lA1 = lA + (256 + w*64)*8;
  bf16_t* lB0 = lB + (w*64)*8;
  bf16_t* lB1 = lB + (256 + w*64)*8;

  for (int k0 = 0; k0 < K; k0 += 32) {
    __builtin_amdgcn_global_load_lds((const GLOBAL_AS void*)(a0 + k0), (LDS_AS void*)lA0, 16, 0, 0);
    __builtin_amdgcn_global_load_lds((const GLOBAL_AS void*)(a1 + k0), (LDS_AS void*)lA1, 16, 0, 0);
    __builtin_amdgcn_global_load_lds((const GLOBAL_AS void*)(b0 + k0), (LDS_AS void*)lB0, 16, 0, 0);
    __builtin_amdgcn_global_load_lds((const GLOBAL_AS void*)(b1 + k0), (LDS_AS void*)lB1, 16, 0, 0);
    __syncthreads();   // drains vmcnt before reads

    bf16x8 af[4], bfr[4];
    #pragma unroll
    for (int mi=0;mi<4;mi++)
      af[mi] = *(const bf16x8*)(lA + (wm*64 + mi*16 + fr)*32 + fq*8);
    #pragma unroll
    for (int ni=0;ni<4;ni++)
      bfr[ni] = *(const bf16x8*)(lB + (wn*64 + ni*16 + fr)*32 + fq*8);
    #pragma unroll
    for (int mi=0;mi<4;mi++)
      #pragma unroll
      for (int ni=0;ni<4;ni++)
        acc[mi][ni] = __builtin_amdgcn_mfma_f32_16x16x32_bf16(af[mi], bfr[ni], acc[mi][ni], 0, 0, 0);
    __syncthreads();   // protect LDS before next stage
  }

  #pragma unroll
  for (int mi=0;mi<4;mi++) {
    #pragma unroll
    for (int ni=0;ni<4;ni++) {
      long row = bm*128 + wm*64 + mi*16 + fq*4;
      long col = bn*128 + wn*64 + ni*16 + fr;
      #pragma unroll
      for (int r=0;r<4;r++) {
        float v = acc[mi][ni][r];
        if (OUT_BF16) ((bf16_t*)Cp)[(row+r)*(long)N + col] = (bf16_t)v;
        else          ((float*)Cp)[(row+r)*(long)N + col] = v;
      }
    }
  }
}

// ---------------------------------------------------------------------------
// beta / g:  per token, 16 dots with W_b rows and 16 with W_a rows (K=2048)
// writes gb_t[bh][s] = {exp(g), beta}
// ---------------------------------------------------------------------------
__global__ __launch_bounds__(64) void betag_kernel(
    const bf16_t* __restrict__ xbf, const float* __restrict__ W_b,
    const float* __restrict__ W_a, const float* __restrict__ dt_bias,
    const float* __restrict__ A_log, float2* __restrict__ gb_t)
{
  const int row  = blockIdx.x;        // token b*S+s
  const int lane = threadIdx.x;
  const int b = row / SS, s = row % SS;

  float xv[32];
  {
    const bf16x8* xr = (const bf16x8*)(xbf + (long)row*DD + lane*32);
    #pragma unroll
    for (int c8=0;c8<4;c8++) {
      bf16x8 v = xr[c8];
      #pragma unroll
      for (int e=0;e<8;e++) xv[c8*8+e] = (float)v[e];
    }
  }

  for (int h=0; h<HH; ++h) {
    const float4* wb4 = (const float4*)(W_b + (long)h*DD + lane*32);
    const float4* wa4 = (const float4*)(W_a + (long)h*DD + lane*32);
    float pb = 0.f, pa = 0.f;
    #pragma unroll
    for (int c4=0;c4<8;c4++) {
      float4 wb = wb4[c4], wa = wa4[c4];
      pb += xv[c4*4+0]*wb.x + xv[c4*4+1]*wb.y + xv[c4*4+2]*wb.z + xv[c4*4+3]*wb.w;
      pa += xv[c4*4+0]*wa.x + xv[c4*4+1]*wa.y + xv[c4*4+2]*wa.z + xv[c4*4+3]*wa.w;
    }
    #pragma unroll
    for (int off=32; off>=1; off>>=1) { pb += __shfl_xor(pb, off); pa += __shfl_xor(pa, off); }
    if (lane == h) {
      float beta = 1.f/(1.f+expf(-pb));
      float tt = pa + dt_bias[h];
      float sp = (tt > 20.f) ? tt : log1pf(expf(tt));
      float g  = -expf(A_log[h]) * sp;
      gb_t[((long)b*HH + h)*SS + s] = make_float2(expf(g), beta);
    }
  }
}

// ---------------------------------------------------------------------------
// conv(K=4 causal depthwise) + bias + silu + q/k l2norm + transpose to [B,H,S,128]
// ---------------------------------------------------------------------------
__global__ __launch_bounds__(128) void conv_norm_kernel(
    const bf16_t* __restrict__ mixed, const float* __restrict__ cw,
    const float* __restrict__ cb, bf16_t* __restrict__ q_t,
    bf16_t* __restrict__ k_t, bf16_t* __restrict__ v_t)
{
  const int blk = blockIdx.x;           // (b*H+h)*S + s
  const int s = blk & (SS-1);
  const int h = (blk >> 11) & (HH-1);
  const int b = blk >> 15;
  const int d = threadIdx.x;

  const int cq = h*128 + d;
  const int ck = 2048 + cq;
  const int cv = 4096 + cq;
  float aq = cb[cq], ak = cb[ck], av = cb[cv];
  const float* wq = cw + (long)cq*4;
  const float* wk = cw + (long)ck*4;
  const float* wv = cw + (long)cv*4;
  #pragma unroll
  for (int tp=0; tp<4; ++tp) {
    int s2 = s - 3 + tp;
    if (s2 >= 0) {
      const bf16_t* rowp = mixed + ((long)b*SS + s2)*CONVC;
      aq += (float)rowp[cq] * wq[tp];
      ak += (float)rowp[ck] * wk[tp];
      av += (float)rowp[cv] * wv[tp];
    }
  }
  aq = aq * (1.f/(1.f+expf(-aq)));
  ak = ak * (1.f/(1.f+expf(-ak)));
  av = av * (1.f/(1.f+expf(-av)));

  float sq = aq*aq, sk = ak*ak;
  #pragma unroll
  for (int off=32; off>=1; off>>=1) { sq += __shfl_xor(sq, off); sk += __shfl_xor(sk, off); }
  __shared__ float red[4];
  const int wv2 = d >> 6;
  if ((d & 63) == 0) { red[wv2*2] = sq; red[wv2*2+1] = sk; }
  __syncthreads();
  float sumq = red[0] + red[2];
  float sumk = red[1] + red[3];

  const long obase = ((long)(b*HH + h)*SS + s)*128 + d;
  q_t[obase] = (bf16_t)(aq * rsqrtf(sumq + 1e-6f) * 0.08838834764831845f);  // * DK^-0.5
  k_t[obase] = (bf16_t)(ak * rsqrtf(sumk + 1e-6f));
  v_t[obase] = (bf16_t)av;
}

// ---------------------------------------------------------------------------
// gated delta rule recurrence. One wave per (b,h, 4-column group).
// lane = cl*16+rg : column j = cg*4+cl, rows i = rg*8..+8 (4 f32x2 pairs).
// 1024 waves (4/CU — every SIMD occupied). Depth-4 buffer rotation.
// 16-lane DPP butterfly (xor1,xor2,~xor4,~xor8). po reduced in batches of 4.
// ---------------------------------------------------------------------------
__global__ __launch_bounds__(64) void rec_kernel(
    const bf16_t* __restrict__ q_t, const bf16_t* __restrict__ k_t,
    const bf16_t* __restrict__ v_t, const float2* __restrict__ gb_t,
    float* __restrict__ o)
{
  // XCD swizzle: 1024 blocks = 8 XCDs * 128; all 32 cg-waves of a bh on one XCD
  const int bid  = blockIdx.x;
  const int blk  = (bid & 7)*128 + (bid >> 3);
  const int cg   = blk & 31;
  const int bh   = blk >> 5;
  const int lane = threadIdx.x;
  const int cl   = lane >> 4;        // 0..3
  const int rg   = lane & 15;        // 0..15
  const int j    = cg*4 + cl;        // column 0..127
  const int i0   = rg*8;             // first of 8 rows
  const int b    = bh >> 4, h = bh & 15;

  const bf16_t* qb  = q_t + (long)bh*SS*128 + i0;
  const bf16_t* kb  = k_t + (long)bh*SS*128 + i0;
  const bf16_t* vb  = v_t + (long)bh*SS*128 + j;
  const float2* gbb = gb_t + (long)bh*SS;
  float* ob = o + (long)b*SS*HH*128 + h*128 + j;

  f32x2 st[4];
  #pragma unroll
  for (int r=0;r<4;r++) st[r] = (f32x2){0.f,0.f};

  bf16x8 Ak, Aq; float Av; float2 Agb;
  bf16x8 Bk, Bq; float Bv; float2 Bgb;
  bf16x8 Ck, Cq; float Cv; float2 Cgb;
  bf16x8 Dk, Dq; float Dv; float2 Dgb;
  Ak = *(const bf16x8*)(kb);          Aq = *(const bf16x8*)(qb);
  Av = (float)vb[0];                  Agb = gbb[0];
  Bk = *(const bf16x8*)(kb + 128);    Bq = *(const bf16x8*)(qb + 128);
  Bv = (float)vb[128];                Bgb = gbb[1];
  Ck = *(const bf16x8*)(kb + 256);    Cq = *(const bf16x8*)(qb + 256);
  Cv = (float)vb[256];                Cgb = gbb[2];
  Dk = *(const bf16x8*)(kb + 384);    Dq = *(const bf16x8*)(qb + 384);
  Dv = (float)vb[384];                Dgb = gbb[3];

  float porw[4];   // raw per-lane partial outputs, reduced every 4 steps

  // bf16 pair (one u32) -> f32x2 via shift/mask
#define CVT_PAIR(dst, w) { (dst)[0] = __int_as_float((int)((w) << 16)); \
                           (dst)[1] = __int_as_float((int)((w) & 0xFFFF0000u)); }

#define REC_STEP(S, T, Xk, Xq, Xv, Xgb)                                        \
  {                                                                            \
    f32x2 kk[4], qq[4];                                                        \
    {                                                                          \
      u32x4 w0 = __builtin_bit_cast(u32x4, Xk);                                \
      u32x4 y0 = __builtin_bit_cast(u32x4, Xq);                                \
      _Pragma("unroll")                                                        \
      for (int e=0;e<4;e++) { CVT_PAIR(kk[e], w0[e]); CVT_PAIR(qq[e], y0[e]); }\
    }                                                                          \
    const float eg  = Xgb.x;                                                   \
    const float bet = Xgb.y;                                                   \
    const float cv  = Xv;                                                      \
    /* registers free after CVT: reload this buffer for step S+4 */            \
    {                                                                          \
      const long sn = ((S)+4 < SS) ? (S)+4 : (SS-1);                           \
      Xk  = *(const bf16x8*)(kb + sn*128);                                     \
      Xq  = *(const bf16x8*)(qb + sn*128);                                     \
      Xv  = (float)vb[sn*128];                                                 \
      Xgb = gbb[sn];                                                           \
    }                                                                          \
    f32x2 p2 = kk[0]*st[0];                                                    \
    _Pragma("unroll")                                                          \
    for (int r=1;r<4;r++) p2 += kk[r]*st[r];                                   \
    float p = p2[0] + p2[1];                                                   \
    p = DPP_ADD(p, 0xB1);   /* xor1 */                                         \
    p = DPP_ADD(p, 0x4E);   /* xor2 */                                         \
    p = DPP_ADD(p, 0x141);  /* half_mirror == xor4 after equalization */       \
    p = DPP_ADD(p, 0x140);  /* row_mirror  == xor8 after equalization */       \
    const float delta = (cv - p*eg)*bet;                                       \
    const f32x2 d2  = (f32x2){delta, delta};                                   \
    const f32x2 eg2 = (f32x2){eg, eg};                                         \
    f32x2 po2 = (f32x2){0.f,0.f};                                              \
    _Pragma("unroll")                                                          \
    for (int r=0;r<4;r++) {                                                    \
      st[r] = st[r]*eg2 + kk[r]*d2;                                            \
      po2  += qq[r]*st[r];                                                     \
    }                                                                          \
    porw[T] = po2[0] + po2[1];                                                 \
  }

  for (int s=0; s<SS; s+=4) {
    REC_STEP(s,   0, Ak, Aq, Av, Agb);
    REC_STEP(s+1, 1, Bk, Bq, Bv, Bgb);
    REC_STEP(s+2, 2, Ck, Cq, Cv, Cgb);
    REC_STEP(s+3, 3, Dk, Dq, Dv, Dgb);
    // batch-reduce the 4 independent output partials (pipelined DPP chains)
    float r0 = porw[0], r1 = porw[1], r2 = porw[2], r3 = porw[3];
    r0 = DPP_ADD(r0, 0xB1);  r1 = DPP_ADD(r1, 0xB1);
    r2 = DPP_ADD(r2, 0xB1);  r3 = DPP_ADD(r3, 0xB1);
    r0 = DPP_ADD(r0, 0x4E);  r1 = DPP_ADD(r1, 0x4E);
    r2 = DPP_ADD(r2, 0x4E);  r3 = DPP_ADD(r3, 0x4E);
    r0 = DPP_ADD(r0, 0x141); r1 = DPP_ADD(r1, 0x141);
    r2 = DPP_ADD(r2, 0x141); r3 = DPP_ADD(r3, 0x141);
    r0 = DPP_ADD(r0, 0x140); r1 = DPP_ADD(r1, 0x140);
    r2 = DPP_ADD(r2, 0x140); r3 = DPP_ADD(r3, 0x140);
    if (rg == 0) {
      ob[(long)(s+0)*HH*128] = r0;
      ob[(long)(s+1)*HH*128] = r1;
      ob[(long)(s+2)*HH*128] = r2;
      ob[(long)(s+3)*HH*128] = r3;
    }
  }
#undef REC_STEP
#undef CVT_PAIR
}

// ---------------------------------------------------------------------------
// RMSNorm over DV + (1+nw) + silu(z) gate; writes bf16 for final GEMM
// ---------------------------------------------------------------------------
__global__ __launch_bounds__(128) void norm_gate_kernel(
    const float* __restrict__ o, const bf16_t* __restrict__ z,
    const float* __restrict__ nw, bf16_t* __restrict__ og)
{
  const long row = blockIdx.x;      // (b*S+s)*H + h
  const int d = threadIdx.x;
  float x = o[row*128 + d];
  float ss = x*x;
  #pragma unroll
  for (int off=32; off>=1; off>>=1) ss += __shfl_xor(ss, off);
  __shared__ float red[2];
  if ((d & 63) == 0) red[d>>6] = ss;
  __syncthreads();
  float mean = (red[0] + red[1]) * (1.f/128.f);
  float zn = (float)z[row*128 + d];
  float val = x * rsqrtf(mean + 1e-6f) * (1.f + nw[d]) * (zn * (1.f/(1.f+expf(-zn))));
  og[row*128 + d] = (bf16_t)val;
}

// ---------------------------------------------------------------------------
extern "C" void kernel_launch(void* const* d_in, const int* in_sizes, int n_in,
                              void* d_out, int out_size, void* d_ws, size_t ws_size,
                              hipStream_t stream)
{
  const float* hs    = (const float*)d_in[0];
  const float* amask = (const float*)d_in[1];
  const float* Wqkv  = (const float*)d_in[2];
  const float* convw = (const float*)d_in[3];
  const float* convb = (const float*)d_in[4];
  const float* Wz    = (const float*)d_in[5];
  const float* Wb    = (const float*)d_in[6];
  const float* Wa    = (const float*)d_in[7];
  const float* dtb   = (const float*)d_in[8];
  const float* Alog  = (const float*)d_in[9];
  const float* nw    = (const float*)d_in[10];
  const float* Wout  = (const float*)d_in[11];

  char* p = (char*)d_ws;
  auto alloc = [&](size_t bytes) { char* r = p; p += (bytes + 255) & ~(size_t)255; return r; };
  bf16_t* x_bf    = (bf16_t*)alloc((size_t)MM*DD*2);        // 16 MB (og aliases later)
  bf16_t* wqkv_bf = (bf16_t*)alloc((size_t)CONVC*DD*2);     // 24 MB (wout_bf aliases later)
  bf16_t* wz_bf   = (bf16_t*)alloc((size_t)DD*DD*2);        // 8 MB
  bf16_t* mixed   = (bf16_t*)alloc((size_t)MM*CONVC*2);     // 48 MB (obuf aliases later)
  bf16_t* zbuf    = (bf16_t*)alloc((size_t)MM*DD*2);        // 16 MB
  bf16_t* q_t     = (bf16_t*)alloc((size_t)MM*DD*2);        // 16 MB
  bf16_t* k_t     = (bf16_t*)alloc((size_t)MM*DD*2);        // 16 MB
  bf16_t* v_t     = (bf16_t*)alloc((size_t)MM*DD*2);        // 16 MB
  float2* gb_t    = (float2*)alloc((size_t)BB*HH*SS*8);
  size_t need = (size_t)(p - (char*)d_ws);
  if (ws_size < need) return;   // clean fail (diagnosable as absmax=poison)

  // liveness-based aliases
  bf16_t* wout_bf = wqkv_bf;          // cast after GEMM1 consumed wqkv_bf
  float*  obuf    = (float*)mixed;    // rec writes after conv consumed mixed (32MB <= 48MB)
  bf16_t* og      = x_bf;             // written after last read of x_bf (z-GEMM)

  cast_x_kernel<<<2048, 256, 0, stream>>>(hs, amask, x_bf, (long)MM*DD);
  cast_w_kernel<<<2048, 256, 0, stream>>>(Wqkv, wqkv_bf, (long)CONVC*DD);
  cast_w_kernel<<<1024, 256, 0, stream>>>(Wz,   wz_bf,   (long)DD*DD);

  betag_kernel<<<MM, 64, 0, stream>>>(x_bf, Wb, Wa, dtb, Alog, gb_t);

  gemm_bt<true><<<dim3(32,48), 256, 0, stream>>>(x_bf, wqkv_bf, mixed, MM, CONVC, DD);
  cast_w_kernel<<<1024, 256, 0, stream>>>(Wout, wout_bf, (long)DD*DD);
  gemm_bt<true><<<dim3(32,16), 256, 0, stream>>>(x_bf, wz_bf,   zbuf,  MM, DD, DD);

  conv_norm_kernel<<<BB*HH*SS, 128, 0, stream>>>(mixed, convw, convb, q_t, k_t, v_t);

  rec_kernel<<<BB*HH*32, 64, 0, stream>>>(q_t, k_t, v_t, gb_t, obuf);

  norm_gate_kernel<<<MM*HH, 128, 0, stream>>>(obuf, zbuf, nw, og);

  gemm_bt<false><<<dim3(32,16), 256, 0, stream>>>(og, wout_bf, d_out, MM, DD, DD);
}

// Round 6
// 786.349 us; speedup vs baseline: 2.2479x; 1.2327x over previous
//
#include <hip/hip_runtime.h>
#include <hip/hip_bf16.h>
#include <math.h>

// Problem constants
#define BB 2
#define SS 2048
#define DD 2048
#define HH 16
#define CONVC 6144
#define MM (BB*SS)   // 4096 tokens

// chunked delta-rule constants
#define CH 64        // chunk length
#define NCH 32       // chunks per sequence
#define CD_KTS 0
#define CD_TV  16384
#define CD_TP  32768
#define CD_AQ  40960
#define CD_PV  49152
#define CD_PC  49408
#define CD_STRIDE 49664

typedef __bf16 bf16_t;
typedef __bf16 bf16x8 __attribute__((ext_vector_type(8)));
typedef __bf16 bf16x4 __attribute__((ext_vector_type(4)));
typedef float  f32x4  __attribute__((ext_vector_type(4)));

#define GLOBAL_AS __attribute__((address_space(1)))
#define LDS_AS    __attribute__((address_space(3)))

#define MFMA16(a,b,c) __builtin_amdgcn_mfma_f32_16x16x32_bf16((a),(b),(c),0,0,0)

// ---------------------------------------------------------------------------
// Cast kernels
// ---------------------------------------------------------------------------
__global__ __launch_bounds__(256) void cast_x_kernel(
    const float* __restrict__ in, const float* __restrict__ mask,
    bf16_t* __restrict__ out, long n)
{
  long n4 = n >> 2;
  for (long i = (long)blockIdx.x*256 + threadIdx.x; i < n4; i += (long)gridDim.x*256) {
    float4 v = ((const float4*)in)[i];
    float m = mask[(i*4) / DD];
    bf16x4 o4;
    o4[0]=(bf16_t)(v.x*m); o4[1]=(bf16_t)(v.y*m);
    o4[2]=(bf16_t)(v.z*m); o4[3]=(bf16_t)(v.w*m);
    ((bf16x4*)out)[i] = o4;
  }
}

__global__ __launch_bounds__(256) void cast_w_kernel(
    const float* __restrict__ in, bf16_t* __restrict__ out, long n)
{
  long n4 = n >> 2;
  for (long i = (long)blockIdx.x*256 + threadIdx.x; i < n4; i += (long)gridDim.x*256) {
    float4 v = ((const float4*)in)[i];
    bf16x4 o4;
    o4[0]=(bf16_t)v.x; o4[1]=(bf16_t)v.y; o4[2]=(bf16_t)v.z; o4[3]=(bf16_t)v.w;
    ((bf16x4*)out)[i] = o4;
  }
}

// ---------------------------------------------------------------------------
// bf16 MFMA GEMM: C[M,N] = A[M,K] * B[N,K]^T   (m97-style 128x128 tile, BK=32)
// ---------------------------------------------------------------------------
template<bool OUT_BF16>
__global__ __launch_bounds__(256) void gemm_bt(
    const bf16_t* __restrict__ A, const bf16_t* __restrict__ Bm,
    void* __restrict__ Cp, int M, int N, int K)
{
  __shared__ __align__(16) bf16_t lA[128*32];
  __shared__ __align__(16) bf16_t lB[128*32];
  const int t    = threadIdx.x;
  const int lane = t & 63;
  const int w    = t >> 6;       // wave 0..3
  const int wm   = w >> 1, wn = w & 1;
  const int fr   = lane & 15, fq = lane >> 4;
  const long bm  = blockIdx.x, bn = blockIdx.y;

  f32x4 acc[4][4];
  #pragma unroll
  for (int i=0;i<4;i++)
    #pragma unroll
    for (int jj=0;jj<4;jj++) acc[i][jj] = (f32x4){0.f,0.f,0.f,0.f};

  const int r1 = t >> 2;
  const int kb = (t & 3) << 3;
  const bf16_t* a0 = A  + (bm*128 + r1)*(long)K + kb;
  const bf16_t* a1 = a0 + 64*(long)K;
  const bf16_t* b0 = Bm + (bn*128 + r1)*(long)K + kb;
  const bf16_t* b1 = b0 + 64*(long)K;
  bf16_t* lA0 = lA + (w*64)*8;        // wave-uniform LDS bases
  bf16_t* lA1 = lA + (256 + w*64)*8;
  bf16_t* lB0 = lB + (w*64)*8;
  bf16_t* lB1 = lB + (256 + w*64)*8;

  for (int k0 = 0; k0 < K; k0 += 32) {
    __builtin_amdgcn_global_load_lds((const GLOBAL_AS void*)(a0 + k0), (LDS_AS void*)lA0, 16, 0, 0);
    __builtin_amdgcn_global_load_lds((const GLOBAL_AS void*)(a1 + k0), (LDS_AS void*)lA1, 16, 0, 0);
    __builtin_amdgcn_global_load_lds((const GLOBAL_AS void*)(b0 + k0), (LDS_AS void*)lB0, 16, 0, 0);
    __builtin_amdgcn_global_load_lds((const GLOBAL_AS void*)(b1 + k0), (LDS_AS void*)lB1, 16, 0, 0);
    __syncthreads();   // drains vmcnt before reads

    bf16x8 af[4], bfr[4];
    #pragma unroll
    for (int mi=0;mi<4;mi++)
      af[mi] = *(const bf16x8*)(lA + (wm*64 + mi*16 + fr)*32 + fq*8);
    #pragma unroll
    for (int ni=0;ni<4;ni++)
      bfr[ni] = *(const bf16x8*)(lB + (wn*64 + ni*16 + fr)*32 + fq*8);
    #pragma unroll
    for (int mi=0;mi<4;mi++)
      #pragma unroll
      for (int ni=0;ni<4;ni++)
        acc[mi][ni] = MFMA16(af[mi], bfr[ni], acc[mi][ni]);
    __syncthreads();   // protect LDS before next stage
  }

  #pragma unroll
  for (int mi=0;mi<4;mi++) {
    #pragma unroll
    for (int ni=0;ni<4;ni++) {
      long row = bm*128 + wm*64 + mi*16 + fq*4;
      long col = bn*128 + wn*64 + ni*16 + fr;
      #pragma unroll
      for (int r=0;r<4;r++) {
        float v = acc[mi][ni][r];
        if (OUT_BF16) ((bf16_t*)Cp)[(row+r)*(long)N + col] = (bf16_t)v;
        else          ((float*)Cp)[(row+r)*(long)N + col] = v;
      }
    }
  }
}

// ---------------------------------------------------------------------------
// beta / g:  per token, 16 dots with W_b rows and 16 with W_a rows (K=2048)
// writes gb_t[bh][s] = {g (log decay), beta}
// ---------------------------------------------------------------------------
__global__ __launch_bounds__(64) void betag_kernel(
    const bf16_t* __restrict__ xbf, const float* __restrict__ W_b,
    const float* __restrict__ W_a, const float* __restrict__ dt_bias,
    const float* __restrict__ A_log, float2* __restrict__ gb_t)
{
  const int row  = blockIdx.x;        // token b*S+s
  const int lane = threadIdx.x;
  const int b = row / SS, s = row % SS;

  float xv[32];
  {
    const bf16x8* xr = (const bf16x8*)(xbf + (long)row*DD + lane*32);
    #pragma unroll
    for (int c8=0;c8<4;c8++) {
      bf16x8 v = xr[c8];
      #pragma unroll
      for (int e=0;e<8;e++) xv[c8*8+e] = (float)v[e];
    }
  }

  for (int h=0; h<HH; ++h) {
    const float4* wb4 = (const float4*)(W_b + (long)h*DD + lane*32);
    const float4* wa4 = (const float4*)(W_a + (long)h*DD + lane*32);
    float pb = 0.f, pa = 0.f;
    #pragma unroll
    for (int c4=0;c4<8;c4++) {
      float4 wb = wb4[c4], wa = wa4[c4];
      pb += xv[c4*4+0]*wb.x + xv[c4*4+1]*wb.y + xv[c4*4+2]*wb.z + xv[c4*4+3]*wb.w;
      pa += xv[c4*4+0]*wa.x + xv[c4*4+1]*wa.y + xv[c4*4+2]*wa.z + xv[c4*4+3]*wa.w;
    }
    #pragma unroll
    for (int off=32; off>=1; off>>=1) { pb += __shfl_xor(pb, off); pa += __shfl_xor(pa, off); }
    if (lane == h) {
      float beta = 1.f/(1.f+expf(-pb));
      float tt = pa + dt_bias[h];
      float sp = (tt > 20.f) ? tt : log1pf(expf(tt));
      float g  = -expf(A_log[h]) * sp;
      gb_t[((long)b*HH + h)*SS + s] = make_float2(g, beta);
    }
  }
}

// ---------------------------------------------------------------------------
// conv(K=4 causal depthwise) + bias + silu + q/k l2norm + transpose to [B,H,S,128]
// ---------------------------------------------------------------------------
__global__ __launch_bounds__(128) void conv_norm_kernel(
    const bf16_t* __restrict__ mixed, const float* __restrict__ cw,
    const float* __restrict__ cb, bf16_t* __restrict__ q_t,
    bf16_t* __restrict__ k_t, bf16_t* __restrict__ v_t)
{
  const int blk = blockIdx.x;           // (b*H+h)*S + s
  const int s = blk & (SS-1);
  const int h = (blk >> 11) & (HH-1);
  const int b = blk >> 15;
  const int d = threadIdx.x;

  const int cq = h*128 + d;
  const int ck = 2048 + cq;
  const int cv = 4096 + cq;
  float aq = cb[cq], ak = cb[ck], av = cb[cv];
  const float* wq = cw + (long)cq*4;
  const float* wk = cw + (long)ck*4;
  const float* wv = cw + (long)cv*4;
  #pragma unroll
  for (int tp=0; tp<4; ++tp) {
    int s2 = s - 3 + tp;
    if (s2 >= 0) {
      const bf16_t* rowp = mixed + ((long)b*SS + s2)*CONVC;
      aq += (float)rowp[cq] * wq[tp];
      ak += (float)rowp[ck] * wk[tp];
      av += (float)rowp[cv] * wv[tp];
    }
  }
  aq = aq * (1.f/(1.f+expf(-aq)));
  ak = ak * (1.f/(1.f+expf(-ak)));
  av = av * (1.f/(1.f+expf(-av)));

  float sq = aq*aq, sk = ak*ak;
  #pragma unroll
  for (int off=32; off>=1; off>>=1) { sq += __shfl_xor(sq, off); sk += __shfl_xor(sk, off); }
  __shared__ float red[4];
  const int wv2 = d >> 6;
  if ((d & 63) == 0) { red[wv2*2] = sq; red[wv2*2+1] = sk; }
  __syncthreads();
  float sumq = red[0] + red[2];
  float sumk = red[1] + red[3];

  const long obase = ((long)(b*HH + h)*SS + s)*128 + d;
  q_t[obase] = (bf16_t)(aq * rsqrtf(sumq + 1e-6f) * 0.08838834764831845f);  // * DK^-0.5
  k_t[obase] = (bf16_t)(ak * rsqrtf(sumk + 1e-6f));
  v_t[obase] = (bf16_t)av;
}

// ---------------------------------------------------------------------------
// Phase A (per bh,chunk): build Tp/Aq/TV/KTs/pv/PC into cdata.
//   Lf[t,i] = b_t exp(gc_t-gc_i) (k_t.k_i), i<t
//   Tmat = (I + Lf)^{-1} diag(b)  (forward substitution)
//   Tp = Tmat diag(p); TV = Tmat V; Aq[t,i] = exp(gc_t-gc_i)(q_t.k_i) i<=t
//   KTs[dk,i] = exp(gc_C-gc_i) k_i[dk]
// ---------------------------------------------------------------------------
__global__ __launch_bounds__(256) void chunkA_kernel(
    const bf16_t* __restrict__ q_t, const bf16_t* __restrict__ k_t,
    const bf16_t* __restrict__ v_t, const float2* __restrict__ gb_t,
    char* __restrict__ cdata)
{
  extern __shared__ char smem[];
  bf16_t* lK  = (bf16_t*)(smem);            // [64][136]
  bf16_t* lQ  = (bf16_t*)(smem + 17408);    // [64][136]
  bf16_t* lVT = (bf16_t*)(smem + 34816);    // [128][72]
  float*  lLf = (float*)(smem + 53248);     // [64][65]
  float*  lXf = (float*)(smem + 69888);     // [64][65]
  float*  gcv = (float*)(smem + 86528);     // [64]
  float*  pvv = (float*)(smem + 86784);     // [64]
  float*  bvv = (float*)(smem + 87040);     // [64]

  const int cd = blockIdx.x;
  const int bh = cd >> 5, c = cd & 31;
  const int t = threadIdx.x;
  const int lane = t & 63, w = t >> 6;
  const int fr = lane & 15, fq = lane >> 4;

  const bf16_t* kg = k_t + ((long)bh*SS + c*CH)*128;
  const bf16_t* qg = q_t + ((long)bh*SS + c*CH)*128;
  const bf16_t* vg = v_t + ((long)bh*SS + c*CH)*128;
  char* cdp = cdata + (long)cd*CD_STRIDE;

  #pragma unroll
  for (int ib=0; ib<4; ib++) {
    int e0 = (t + 256*ib)*8;
    int r = e0 >> 7, cc = e0 & 127;
    *(bf16x8*)&lK[r*136+cc] = *(const bf16x8*)(kg + e0);
    *(bf16x8*)&lQ[r*136+cc] = *(const bf16x8*)(qg + e0);
    bf16x8 v8 = *(const bf16x8*)(vg + e0);
    #pragma unroll
    for (int e=0;e<8;e++) lVT[(cc+e)*72 + r] = v8[e];
  }
  if (t < 64) {
    float2 gb = gb_t[(long)bh*SS + c*CH + t];
    gcv[t] = gb.x;
    bvv[t] = gb.y;
  }
  __syncthreads();
  if (t == 0) {
    float run = 0.f;
    for (int i=0;i<CH;i++){ run += gcv[i]; gcv[i] = run; }
  }
  __syncthreads();
  if (t < 64) pvv[t] = expf(gcv[t]);

  // G = K K^T, Gq = Q K^T  (wave strip rows 16w)
  {
    f32x4 accG[4], accQ[4];
    #pragma unroll
    for (int tn=0;tn<4;tn++){ accG[tn]=(f32x4){0,0,0,0}; accQ[tn]=(f32x4){0,0,0,0}; }
    #pragma unroll
    for (int ks=0;ks<4;ks++) {
      bf16x8 aK = *(const bf16x8*)&lK[(w*16+fr)*136 + fq*8 + ks*32];
      bf16x8 aQ = *(const bf16x8*)&lQ[(w*16+fr)*136 + fq*8 + ks*32];
      #pragma unroll
      for (int tn=0;tn<4;tn++) {
        bf16x8 bK = *(const bf16x8*)&lK[(tn*16+fr)*136 + fq*8 + ks*32];
        accG[tn] = MFMA16(aK, bK, accG[tn]);
        accQ[tn] = MFMA16(aQ, bK, accQ[tn]);
      }
    }
    bf16_t* aqg = (bf16_t*)(cdp + CD_AQ);
    #pragma unroll
    for (int tn=0;tn<4;tn++) {
      #pragma unroll
      for (int r=0;r<4;r++) {
        int tt = w*16 + fq*4 + r;
        int ii = tn*16 + fr;
        float er = expf(gcv[tt] - gcv[ii]);
        lLf[tt*65 + ii] = (ii < tt) ? bvv[tt]*er*accG[tn][r] : 0.f;
        aqg[tt*64 + ii] = (bf16_t)((ii <= tt) ? er*accQ[tn][r] : 0.f);
      }
    }
  }
  #pragma unroll
  for (int ib=0; ib<16; ib++) {
    int idx = t + ib*256; int r = idx>>6, cc = idx&63;
    lXf[r*65+cc] = (r==cc) ? bvv[r] : 0.f;
  }
  __syncthreads();

  // forward elimination: X[t] -= Lf[t][i] * X[i]
  {
    const int jj = t & 63, rg = t >> 6;
    for (int i=0; i<CH-1; i++) {
      float xi = lXf[i*65 + jj];
      for (int tr = i+1+rg; tr < CH; tr += 4)
        lXf[tr*65 + jj] = fmaf(-lLf[tr*65 + i], xi, lXf[tr*65 + jj]);
      __syncthreads();
    }
  }

  // Tp store + bf16 copy of Tmat (reuse lLf region)
  bf16_t* lXb = (bf16_t*)lLf;   // [64][72]
  {
    bf16_t* tpg = (bf16_t*)(cdp + CD_TP);
    #pragma unroll
    for (int ib=0; ib<16; ib++) {
      int idx = t + ib*256; int r = idx>>6, cc = idx&63;
      float xv = lXf[r*65+cc];
      tpg[r*64+cc] = (bf16_t)(xv * pvv[cc]);
      lXb[r*72+cc] = (bf16_t)xv;
    }
  }
  __syncthreads();

  // TV = Tmat @ V : C[t][dv] = sum_i Xb[t][i] * VT[dv][i]
  {
    f32x4 acc[8];
    #pragma unroll
    for (int tn=0;tn<8;tn++) acc[tn]=(f32x4){0,0,0,0};
    #pragma unroll
    for (int ks=0;ks<2;ks++) {
      bf16x8 aX = *(const bf16x8*)&lXb[(w*16+fr)*72 + fq*8 + ks*32];
      #pragma unroll
      for (int tn=0;tn<8;tn++) {
        bf16x8 bV = *(const bf16x8*)&lVT[(tn*16+fr)*72 + fq*8 + ks*32];
        acc[tn] = MFMA16(aX, bV, acc[tn]);
      }
    }
    bf16_t* tvg = (bf16_t*)(cdp + CD_TV);
    #pragma unroll
    for (int tn=0;tn<8;tn++)
      #pragma unroll
      for (int r=0;r<4;r++) {
        int tt = w*16 + fq*4 + r, dv = tn*16 + fr;
        tvg[tt*128 + dv] = (bf16_t)acc[tn][r];
      }
  }

  // KTs[dk][i] = K[i][dk] * exp(gc_C - gc_i)
  {
    bf16_t* ktg = (bf16_t*)(cdp + CD_KTS);
    int dk = t >> 1, c0 = (t & 1)*32;
    float g63 = gcv[63];
    bf16_t tmp[32];
    #pragma unroll
    for (int i2=0;i2<32;i2++) {
      int i = c0 + i2;
      tmp[i2] = (bf16_t)((float)lK[i*136 + dk] * expf(g63 - gcv[i]));
    }
    #pragma unroll
    for (int s8=0;s8<4;s8++)
      *(bf16x8*)&ktg[dk*64 + c0 + s8*8] = *(bf16x8*)&tmp[s8*8];
  }
  if (t < 64) ((float*)(cdp + CD_PV))[t] = pvv[t];
  if (t == 0) *((float*)(cdp + CD_PC)) = expf(gcv[63]);
}

// ---------------------------------------------------------------------------
// Phase B: serial over 32 chunks per (bh, dv-split of 32).
//   X=K S; Xq=Q S; D = TV - Tp X; O = diag(p) Xq + Aq D; S = PC*S + KTs D
// ---------------------------------------------------------------------------
__global__ __launch_bounds__(256) void chunkB_kernel(
    const bf16_t* __restrict__ q_t, const bf16_t* __restrict__ k_t,
    const char* __restrict__ cdata, bf16_t* __restrict__ obuf)
{
  extern __shared__ char smem[];
  float*  lS   = (float*)(smem);             // [32][132]  S[dv][dk]
  bf16_t* lSb  = (bf16_t*)(smem + 16896);    // [32][136]
  bf16_t* lK   = (bf16_t*)(smem + 25600);    // [64][136]
  bf16_t* lQ   = (bf16_t*)(smem + 43008);    // [64][136]
  bf16_t* lTp  = (bf16_t*)(smem + 60416);    // [64][72]
  bf16_t* lAq  = (bf16_t*)(smem + 69632);    // [64][72]
  bf16_t* lKT  = (bf16_t*)(smem + 78848);    // [128][72]
  bf16_t* lXT  = (bf16_t*)(smem + 97280);    // [32][72]
  bf16_t* lDT  = (bf16_t*)(smem + 101888);   // [32][72]
  float*  lpv  = (float*)(smem + 106496);    // [64]
  float*  lPC  = (float*)(smem + 106752);

  const int bid = blockIdx.x;
  const int lb  = (bid & 7)*16 + (bid >> 3);   // same-bh blocks on one XCD
  const int bh = lb >> 2, sp = lb & 3;
  const int dv0 = sp*32;
  const int b = bh >> 4, h = bh & 15;
  const int t = threadIdx.x, lane = t & 63, w = t >> 6;
  const int fr = lane & 15, fq = lane >> 4;

  #pragma unroll
  for (int ib=0; ib<16; ib++) {
    int idx = t + ib*256; int r = idx>>7, cc = idx&127;
    lS[r*132+cc] = 0.f;
    lSb[r*136+cc] = (bf16_t)0.f;
  }

  const bf16_t* kg = k_t + (long)bh*SS*128;
  const bf16_t* qg = q_t + (long)bh*SS*128;

  for (int c=0; c<NCH; c++) {
    const char* cdp = cdata + (long)(bh*NCH + c)*CD_STRIDE;
    #pragma unroll
    for (int ib=0; ib<4; ib++) {
      int e0 = (t + 256*ib)*8;
      int r = e0 >> 7, cc = e0 & 127;
      *(bf16x8*)&lK[r*136+cc] = *(const bf16x8*)(kg + (long)c*CH*128 + e0);
      *(bf16x8*)&lQ[r*136+cc] = *(const bf16x8*)(qg + (long)c*CH*128 + e0);
    }
    #pragma unroll
    for (int ib=0; ib<2; ib++) {
      int e0 = (t + 256*ib)*8;
      int r = e0 >> 6, cc = e0 & 63;
      *(bf16x8*)&lTp[r*72+cc] = *(const bf16x8*)((const bf16_t*)(cdp+CD_TP) + e0);
      *(bf16x8*)&lAq[r*72+cc] = *(const bf16x8*)((const bf16_t*)(cdp+CD_AQ) + e0);
    }
    #pragma unroll
    for (int ib=0; ib<4; ib++) {
      int e0 = (t + 256*ib)*8;
      int r = e0 >> 6, cc = e0 & 63;
      *(bf16x8*)&lKT[r*72+cc] = *(const bf16x8*)((const bf16_t*)(cdp+CD_KTS) + e0);
    }
    if (t < 64) lpv[t] = ((const float*)(cdp+CD_PV))[t];
    if (t == 0) *lPC = *(const float*)(cdp+CD_PC);
    __syncthreads();

    // X = K Sb, Xq = Q Sb  (M=64 strip/wave, N=32, K=128)
    f32x4 aX[2], aXq[2];
    aX[0]=aX[1]=aXq[0]=aXq[1]=(f32x4){0,0,0,0};
    #pragma unroll
    for (int ks=0; ks<4; ks++) {
      bf16x8 aK = *(const bf16x8*)&lK[(w*16+fr)*136 + fq*8 + ks*32];
      bf16x8 aQ = *(const bf16x8*)&lQ[(w*16+fr)*136 + fq*8 + ks*32];
      #pragma unroll
      for (int tn=0; tn<2; tn++) {
        bf16x8 bS = *(const bf16x8*)&lSb[(tn*16+fr)*136 + fq*8 + ks*32];
        aX[tn]  = MFMA16(aK, bS, aX[tn]);
        aXq[tn] = MFMA16(aQ, bS, aXq[tn]);
      }
    }
    #pragma unroll
    for (int tn=0; tn<2; tn++)
      #pragma unroll
      for (int r=0; r<4; r++)
        lXT[(tn*16+fr)*72 + (w*16+fq*4+r)] = (bf16_t)aX[tn][r];
    __syncthreads();

    // D = TV - Tp X   -> lDT[dv][t] bf16
    {
      f32x4 aD[2]; aD[0]=aD[1]=(f32x4){0,0,0,0};
      #pragma unroll
      for (int ks=0; ks<2; ks++) {
        bf16x8 aT = *(const bf16x8*)&lTp[(w*16+fr)*72 + fq*8 + ks*32];
        #pragma unroll
        for (int tn=0; tn<2; tn++) {
          bf16x8 bX = *(const bf16x8*)&lXT[(tn*16+fr)*72 + fq*8 + ks*32];
          aD[tn] = MFMA16(aT, bX, aD[tn]);
        }
      }
      const bf16_t* tvp = (const bf16_t*)(cdp + CD_TV);
      #pragma unroll
      for (int tn=0; tn<2; tn++)
        #pragma unroll
        for (int r=0; r<4; r++) {
          int tt = w*16+fq*4+r, dv = tn*16+fr;
          float dval = (float)tvp[tt*128 + dv0 + dv] - aD[tn][r];
          lDT[dv*72 + tt] = (bf16_t)dval;
        }
    }
    // scale S by PC (completes before next barrier; RMW adds happen after it)
    {
      float pc = *lPC;
      #pragma unroll
      for (int ib=0; ib<16; ib++) {
        int idx = t + ib*256; int r = idx>>7, cc = idx&127;
        lS[r*132+cc] *= pc;
      }
    }
    __syncthreads();

    // O = diag(p) Xq + Aq D -> obuf ;  S += KTs D
    {
      f32x4 aO[2];
      aO[0]=aO[1]=(f32x4){0,0,0,0};
      f32x4 aS[2][2];
      aS[0][0]=aS[0][1]=aS[1][0]=aS[1][1]=(f32x4){0,0,0,0};
      #pragma unroll
      for (int ks=0; ks<2; ks++) {
        bf16x8 aA  = *(const bf16x8*)&lAq[(w*16+fr)*72 + fq*8 + ks*32];
        bf16x8 bD0 = *(const bf16x8*)&lDT[(0*16+fr)*72 + fq*8 + ks*32];
        bf16x8 bD1 = *(const bf16x8*)&lDT[(1*16+fr)*72 + fq*8 + ks*32];
        aO[0] = MFMA16(aA, bD0, aO[0]);
        aO[1] = MFMA16(aA, bD1, aO[1]);
        #pragma unroll
        for (int mt=0; mt<2; mt++) {
          bf16x8 aK2 = *(const bf16x8*)&lKT[(w*32+mt*16+fr)*72 + fq*8 + ks*32];
          aS[mt][0] = MFMA16(aK2, bD0, aS[mt][0]);
          aS[mt][1] = MFMA16(aK2, bD1, aS[mt][1]);
        }
      }
      #pragma unroll
      for (int tn=0; tn<2; tn++)
        #pragma unroll
        for (int r=0; r<4; r++) {
          int tt = w*16+fq*4+r, dv = tn*16+fr;
          float ov = lpv[tt]*aXq[tn][r] + aO[tn][r];
          obuf[((long)(b*SS + c*CH + tt)*HH + h)*128 + dv0 + dv] = (bf16_t)ov;
        }
      #pragma unroll
      for (int mt=0; mt<2; mt++)
        #pragma unroll
        for (int tn=0; tn<2; tn++)
          #pragma unroll
          for (int r=0; r<4; r++) {
            int dk = w*32+mt*16+fq*4+r, dv = tn*16+fr;
            lS[dv*132 + dk] += aS[mt][tn][r];
          }
    }
    __syncthreads();
    #pragma unroll
    for (int ib=0; ib<16; ib++) {
      int idx = t + ib*256; int r = idx>>7, cc = idx&127;
      lSb[r*136+cc] = (bf16_t)lS[r*132+cc];
    }
    __syncthreads();
  }
}

// ---------------------------------------------------------------------------
// RMSNorm over DV + (1+nw) + silu(z) gate; writes bf16 for final GEMM
// ---------------------------------------------------------------------------
__global__ __launch_bounds__(128) void norm_gate_kernel(
    const bf16_t* __restrict__ o, const bf16_t* __restrict__ z,
    const float* __restrict__ nw, bf16_t* __restrict__ og)
{
  const long row = blockIdx.x;      // (b*S+s)*H + h
  const int d = threadIdx.x;
  float x = (float)o[row*128 + d];
  float ss = x*x;
  #pragma unroll
  for (int off=32; off>=1; off>>=1) ss += __shfl_xor(ss, off);
  __shared__ float red[2];
  if ((d & 63) == 0) red[d>>6] = ss;
  __syncthreads();
  float mean = (red[0] + red[1]) * (1.f/128.f);
  float zn = (float)z[row*128 + d];
  float val = x * rsqrtf(mean + 1e-6f) * (1.f + nw[d]) * (zn * (1.f/(1.f+expf(-zn))));
  og[row*128 + d] = (bf16_t)val;
}

// ---------------------------------------------------------------------------
extern "C" void kernel_launch(void* const* d_in, const int* in_sizes, int n_in,
                              void* d_out, int out_size, void* d_ws, size_t ws_size,
                              hipStream_t stream)
{
  const float* hs    = (const float*)d_in[0];
  const float* amask = (const float*)d_in[1];
  const float* Wqkv  = (const float*)d_in[2];
  const float* convw = (const float*)d_in[3];
  const float* convb = (const float*)d_in[4];
  const float* Wz    = (const float*)d_in[5];
  const float* Wb    = (const float*)d_in[6];
  const float* Wa    = (const float*)d_in[7];
  const float* dtb   = (const float*)d_in[8];
  const float* Alog  = (const float*)d_in[9];
  const float* nw    = (const float*)d_in[10];
  const float* Wout  = (const float*)d_in[11];

  const size_t MB = 1024*1024;
  char* p = (char*)d_ws;
  auto alloc = [&](size_t bytes) { char* r = p; p += (bytes + 255) & ~(size_t)255; return r; };
  bf16_t* x_bf   = (bf16_t*)alloc(16*MB);   // x_bf; later obuf (bf16)
  char*   bigreg = alloc(72*MB);            // wqkv@0 24MB, mixed@24MB 48MB; later cdata@0 48.5MB, wout@64MB
  bf16_t* wz_bf  = (bf16_t*)alloc(8*MB);
  bf16_t* zbuf   = (bf16_t*)alloc(16*MB);   // z; og in-place later
  bf16_t* q_t    = (bf16_t*)alloc(16*MB);
  bf16_t* k_t    = (bf16_t*)alloc(16*MB);
  bf16_t* v_t    = (bf16_t*)alloc(16*MB);
  float2* gb_t   = (float2*)alloc((size_t)BB*HH*SS*8);
  size_t need = (size_t)(p - (char*)d_ws);
  if (ws_size < need) return;   // clean fail (absmax = poison)

  bf16_t* wqkv_bf = (bf16_t*)bigreg;
  bf16_t* mixed   = (bf16_t*)(bigreg + 24*MB);
  char*   cdata   = bigreg;                       // after GEMM1+conv consumed
  bf16_t* wout_bf = (bf16_t*)(bigreg + 64*MB);    // after conv consumed mixed tail
  bf16_t* obuf    = x_bf;                         // after z-GEMM consumed x_bf
  bf16_t* og      = zbuf;                         // in-place gate

  cast_x_kernel<<<2048, 256, 0, stream>>>(hs, amask, x_bf, (long)MM*DD);
  cast_w_kernel<<<2048, 256, 0, stream>>>(Wqkv, wqkv_bf, (long)CONVC*DD);
  cast_w_kernel<<<1024, 256, 0, stream>>>(Wz,   wz_bf,   (long)DD*DD);

  betag_kernel<<<MM, 64, 0, stream>>>(x_bf, Wb, Wa, dtb, Alog, gb_t);

  gemm_bt<true><<<dim3(32,48), 256, 0, stream>>>(x_bf, wqkv_bf, mixed, MM, CONVC, DD);

  conv_norm_kernel<<<BB*HH*SS, 128, 0, stream>>>(mixed, convw, convb, q_t, k_t, v_t);

  cast_w_kernel<<<1024, 256, 0, stream>>>(Wout, wout_bf, (long)DD*DD);
  gemm_bt<true><<<dim3(32,16), 256, 0, stream>>>(x_bf, wz_bf, zbuf, MM, DD, DD);

  chunkA_kernel<<<BB*HH*NCH, 256, 87296, stream>>>(q_t, k_t, v_t, gb_t, cdata);
  chunkB_kernel<<<BB*HH*4, 256, 106768, stream>>>(q_t, k_t, cdata, obuf);

  norm_gate_kernel<<<MM*HH, 128, 0, stream>>>(obuf, zbuf, nw, og);

  gemm_bt<false><<<dim3(32,16), 256, 0, stream>>>(og, wout_bf, d_out, MM, DD, DD);
}